// Round 5
// baseline (474.494 us; speedup 1.0000x reference)
//
#include <hip/hip_runtime.h>
#include <hip/hip_bf16.h>
#include <cstdint>
#include <cstddef>

// ---------------------------------------------------------------------------
// NostARHeadAttention: LN -> {Q(last), K} proj -> RoPE(K) -> 1-query attn
// with V-elimination.
// R7: non-rot K-half eliminated algebraically (fold_c + plain GEMM).  469 us.
// R8: rot GEMM 256^2/BK=64/8-wave dbuf, counted vmcnt, XOR-swizzle. 441.5 us.
// R9: plain GEMM fused into rot GEMM as C-subtile. 401.2 us; rot 93.3 us,
//     MfmaUtil 39.5%. Residual (non-rot) stable ~308 us vs ~75 us modeled ->
//     suspect serial-stage overhead.
// R10: pipeline 8 -> 6 stages. (a) qhead_kernel = gemv8(q)+fold_c fused
//     (q computed per (b,h) block, fold uses in-LDS q). (b) attn_wsum
//     accumulates directly into wsumN via fp32 atomics (prep zeroes it);
//     attn_comb deleted; vgemv divides by Z. part buffer (16 MB) deleted.
// ---------------------------------------------------------------------------

using bf16x8 = __attribute__((ext_vector_type(8))) __bf16;
using f32x4  = __attribute__((ext_vector_type(4))) float;

__device__ __forceinline__ unsigned short f2bf(float f) {
  unsigned u = __float_as_uint(f);
  u += 0x7fffu + ((u >> 16) & 1u);   // RNE
  return (unsigned short)(u >> 16);
}

__device__ __forceinline__ void gld16(const void* g, void* l) {
  __builtin_amdgcn_global_load_lds((__attribute__((address_space(1))) void*)g,
                                   (__attribute__((address_space(3))) void*)l,
                                   16, 0, 0);
}

#define FENCE() asm volatile("" ::: "memory")
#define SBAR()  { FENCE(); __builtin_amdgcn_s_barrier(); FENCE(); }
#define VM9()   asm volatile("s_waitcnt vmcnt(9)" ::: "memory")
#define VM8()   asm volatile("s_waitcnt vmcnt(8)" ::: "memory")
#define VM0()   asm volatile("s_waitcnt vmcnt(0)" ::: "memory")

// ---------------------------------------------------------------------------
// 1. prep: fused ln (0..16383) + rot-only k_w f2bf (16384..18431) +
//    sctab (18432..18687) + ix+hlast+Z-zero (18688..18695) +
//    wsumN zero (18696..18951).
// ---------------------------------------------------------------------------
__global__ __launch_bounds__(256) void prep_kernel(
    const float* __restrict__ hidden, const int* __restrict__ ids,
    const float* __restrict__ gw, const float* __restrict__ gb,
    const float* __restrict__ kw, unsigned short* __restrict__ hs,
    unsigned short* __restrict__ Wk, float2* __restrict__ tab,
    float* __restrict__ hl, float* __restrict__ Z,
    float* __restrict__ wsumN) {
  const int blk = blockIdx.x, tid = threadIdx.x;
  const int wave = tid >> 6, lane = tid & 63;

  if (blk < 16384) {                       // ---- LayerNorm row -> bf16
    const size_t row = blk;
    const float* xr = hidden + row * 2048;
    float4 a = ((const float4*)xr)[tid];
    float4 b = ((const float4*)xr)[tid + 256];
    float s  = a.x + a.y + a.z + a.w + b.x + b.y + b.z + b.w;
    float ss = a.x*a.x + a.y*a.y + a.z*a.z + a.w*a.w +
               b.x*b.x + b.y*b.y + b.z*b.z + b.w*b.w;
    for (int m = 1; m < 64; m <<= 1) { s += __shfl_xor(s, m); ss += __shfl_xor(ss, m); }
    __shared__ float rs[4], rss[4];
    if (lane == 0) { rs[wave] = s; rss[wave] = ss; }
    __syncthreads();
    s  = rs[0] + rs[1] + rs[2] + rs[3];
    ss = rss[0] + rss[1] + rss[2] + rss[3];
    const float mu = s * (1.f / 2048.f);
    const float var = ss * (1.f / 2048.f) - mu * mu;
    const float r = rsqrtf(var + 1e-5f);
    const int i0 = tid * 4, i1 = 1024 + tid * 4;
    ushort4 p0 = {f2bf((a.x - mu) * r * gw[i0 + 0] + gb[i0 + 0]),
                  f2bf((a.y - mu) * r * gw[i0 + 1] + gb[i0 + 1]),
                  f2bf((a.z - mu) * r * gw[i0 + 2] + gb[i0 + 2]),
                  f2bf((a.w - mu) * r * gw[i0 + 3] + gb[i0 + 3])};
    ushort4 p1 = {f2bf((b.x - mu) * r * gw[i1 + 0] + gb[i1 + 0]),
                  f2bf((b.y - mu) * r * gw[i1 + 1] + gb[i1 + 1]),
                  f2bf((b.z - mu) * r * gw[i1 + 2] + gb[i1 + 2]),
                  f2bf((b.w - mu) * r * gw[i1 + 3] + gb[i1 + 3])};
    *(ushort4*)(hs + row * 2048 + i0) = p0;
    *(ushort4*)(hs + row * 2048 + i1) = p1;
  } else if (blk < 18432) {                // ---- rot cols of k_w -> bf16
    // Wk row r (0..1023) <- k_w row (r>>6)*128 + (r&63)  (head-major, 64/head)
    const size_t i4 = (size_t)(blk - 16384) * 256 + tid;   // 16B units
    const int r = (int)(i4 >> 9);
    const int col4 = (int)(i4 & 511);
    const size_t src4 = ((size_t)((r >> 6) * 128 + (r & 63))) * 512 + col4;
    float4 v = ((const float4*)kw)[src4];
    ushort4 o = {f2bf(v.x), f2bf(v.y), f2bf(v.z), f2bf(v.w)};
    ((ushort4*)Wk)[i4] = o;
  } else if (blk < 18688) {                // ---- sin/cos table (8 t / block)
    const int t = (blk - 18432) * 8 + (tid >> 5);
    const int i = tid & 31;
    const float inv = exp2f(-(float)i * (13.287712379549449f / 32.f));
    const float ang = (float)t * inv;
    tab[t * 32 + i] = make_float2(sinf(ang), cosf(ang));
  } else if (blk < 18696) {                // ---- last-token index + LN + Z=0
    const int b = blk - 18688;
    if (tid < 16) Z[b * 16 + tid] = 0.f;
    int best = -1;
    for (int t = tid; t < 2048; t += 256)
      if (ids[b * 2048 + t] != 50257) best = (t > best) ? t : best;
    for (int m = 1; m < 64; m <<= 1) {
      int o = __shfl_xor(best, m);
      best = (o > best) ? o : best;
    }
    __shared__ int rb[4];
    if (lane == 0) rb[wave] = best;
    __syncthreads();
    int ix = rb[0];
    for (int w = 1; w < 4; ++w) ix = (rb[w] > ix) ? rb[w] : ix;
    ix = (ix < 0) ? 0 : ix;
    const float* xr = hidden + ((size_t)b * 2048 + ix) * 2048;
    float4 a = ((const float4*)xr)[tid];
    float4 c = ((const float4*)xr)[tid + 256];
    float s  = a.x + a.y + a.z + a.w + c.x + c.y + c.z + c.w;
    float ss = a.x*a.x + a.y*a.y + a.z*a.z + a.w*a.w +
               c.x*c.x + c.y*c.y + c.z*c.z + c.w*c.w;
    for (int m = 1; m < 64; m <<= 1) { s += __shfl_xor(s, m); ss += __shfl_xor(ss, m); }
    __shared__ float rs2[4], rss2[4];
    if (lane == 0) { rs2[wave] = s; rss2[wave] = ss; }
    __syncthreads();
    s  = rs2[0] + rs2[1] + rs2[2] + rs2[3];
    ss = rss2[0] + rss2[1] + rss2[2] + rss2[3];
    const float mu = s * (1.f / 2048.f);
    const float var = ss * (1.f / 2048.f) - mu * mu;
    const float r = rsqrtf(var + 1e-5f);
    const int i0 = tid * 4, i1 = 1024 + tid * 4;
    float* yo = hl + (size_t)b * 2048;
    yo[i0 + 0] = (a.x - mu) * r * gw[i0 + 0] + gb[i0 + 0];
    yo[i0 + 1] = (a.y - mu) * r * gw[i0 + 1] + gb[i0 + 1];
    yo[i0 + 2] = (a.z - mu) * r * gw[i0 + 2] + gb[i0 + 2];
    yo[i0 + 3] = (a.w - mu) * r * gw[i0 + 3] + gb[i0 + 3];
    yo[i1 + 0] = (c.x - mu) * r * gw[i1 + 0] + gb[i1 + 0];
    yo[i1 + 1] = (c.y - mu) * r * gw[i1 + 1] + gb[i1 + 1];
    yo[i1 + 2] = (c.z - mu) * r * gw[i1 + 2] + gb[i1 + 2];
    yo[i1 + 3] = (c.w - mu) * r * gw[i1 + 3] + gb[i1 + 3];
  } else {                                 // ---- zero wsumN (1 MB)
    const int idx = (blk - 18696) * 256 + tid;
    ((float4*)wsumN)[idx] = (float4){0.f, 0.f, 0.f, 0.f};
  }
}

// ---------------------------------------------------------------------------
// 2. qhead: per (b,h) block: q[b,h,0..128] = hl[b].q_w_rows + q_b  -> qv;
//    then C[b,h,e] = sum_{c>=64} q*k_w rows -> Cpad (bf16), qkb = sum kb*q.
//    Fuses old gemv8(q) + fold_c (removes one serial stage).
// ---------------------------------------------------------------------------
__global__ __launch_bounds__(256) void qhead_kernel(
    const float* __restrict__ hl, const float* __restrict__ qw,
    const float* __restrict__ qbias, const float* __restrict__ kw,
    const float* __restrict__ kb, float* __restrict__ qv,
    unsigned short* __restrict__ Cpad, float* __restrict__ qkb) {
  const int bh = blockIdx.x, b = bh >> 4, h = bh & 15;
  const int tid = threadIdx.x;
  __shared__ float hls[2048];
  __shared__ float qsh[64];
  ((float4*)hls)[tid]       = ((const float4*)(hl + (size_t)b * 2048))[tid];
  ((float4*)hls)[tid + 256] = ((const float4*)(hl + (size_t)b * 2048))[tid + 256];
  __syncthreads();
  if (tid < 128) {                          // ---- q[b,h,tid]
    const float* wr = qw + (size_t)(h * 128 + tid) * 2048;
    float4 a = {0.f, 0.f, 0.f, 0.f};
#pragma unroll 4
    for (int k = 0; k < 512; ++k) {
      const float4 wv = ((const float4*)wr)[k];
      const float4 xv = *(const float4*)(hls + k * 4);
      a.x += wv.x * xv.x; a.y += wv.y * xv.y;
      a.z += wv.z * xv.z; a.w += wv.w * xv.w;
    }
    const float q = a.x + a.y + a.z + a.w + qbias[h * 128 + tid];
    qv[(size_t)bh * 128 + tid] = q;
    if (tid >= 64) qsh[tid - 64] = q;
  }
  __syncthreads();
  // ---- fold_c body --------------------------------------------------------
  const int e0 = tid * 8;
  float acc[8] = {0, 0, 0, 0, 0, 0, 0, 0};
  for (int c = 0; c < 64; ++c) {
    const float qc = qsh[c];
    const float* row = kw + ((size_t)(h * 128 + 64 + c)) * 2048 + e0;
    float4 v0 = *(const float4*)(row);
    float4 v1 = *(const float4*)(row + 4);
    acc[0] += qc * v0.x; acc[1] += qc * v0.y; acc[2] += qc * v0.z; acc[3] += qc * v0.w;
    acc[4] += qc * v1.x; acc[5] += qc * v1.y; acc[6] += qc * v1.z; acc[7] += qc * v1.w;
  }
  unsigned short* dst = Cpad + ((size_t)b * 128 + h) * 2048 + e0;
  ushort4 o0 = {f2bf(acc[0]), f2bf(acc[1]), f2bf(acc[2]), f2bf(acc[3])};
  ushort4 o1 = {f2bf(acc[4]), f2bf(acc[5]), f2bf(acc[6]), f2bf(acc[7])};
  *(ushort4*)(dst) = o0;
  *(ushort4*)(dst + 4) = o1;
  if (tid < 64) {
    float p = kb[h * 128 + 64 + tid] * qsh[tid];
    for (int m = 1; m < 64; m <<= 1) p += __shfl_xor(p, m);
    if (tid == 0) qkb[bh] = p;
  }
}

// ---------------------------------------------------------------------------
// 2c. gemv8 (final out-proj only): Y[8][2048] = X[8][2048] @ W^T + bias.
// ---------------------------------------------------------------------------
__global__ __launch_bounds__(256) void gemv8_kernel(const float* __restrict__ X,
                                                    const float* __restrict__ W,
                                                    const float* __restrict__ bias,
                                                    float* __restrict__ Y) {
  const int tid = threadIdx.x, lane = tid & 63, wave = tid >> 6;
  const int e = blockIdx.x * 4 + wave;
  const float* wr = W + (size_t)e * 2048;
  float p[8] = {0, 0, 0, 0, 0, 0, 0, 0};
#pragma unroll
  for (int it = 0; it < 8; ++it) {
    const int k = it * 256 + lane * 4;
    float4 wv = *(const float4*)(wr + k);
#pragma unroll
    for (int b = 0; b < 8; ++b) {
      float4 xv = *(const float4*)(X + b * 2048 + k);
      p[b] += wv.x * xv.x + wv.y * xv.y + wv.z * xv.z + wv.w * xv.w;
    }
  }
#pragma unroll
  for (int b = 0; b < 8; ++b)
    for (int m = 1; m < 64; m <<= 1) p[b] += __shfl_xor(p[b], m);
  if (lane == 0) {
    const float bb = bias[e];
#pragma unroll
    for (int b = 0; b < 8; ++b) Y[(size_t)b * 2048 + e] = p[b] + bb;
  }
}

// ---------------------------------------------------------------------------
// 3. gemm_kscore_rot: 256^2 tile, BK=64, 8 waves (2Mx4N), double-buffered
//    LDS, counted vmcnt, XOR-swizzled LDS reads (pre-swizzled gld src).
//    FUSED plain score: 16-row C-subtile (4 valid rows = this block's heads)
//    staged by wave0 -> +8 MFMA/ks into accc.  Epilogue: rot dot with rotated
//    q + kb, + shfl'd plain col + qkb, exp(sc-40) -> sw_t, Z atomicAdd.
// ---------------------------------------------------------------------------
__global__ __launch_bounds__(512, 2) void gemm_kscore_rot_kernel(
    const unsigned short* __restrict__ A, const unsigned short* __restrict__ W,
    const unsigned short* __restrict__ Cpad, const float* __restrict__ qkb,
    const float* __restrict__ kb, const float* __restrict__ qv,
    const float2* __restrict__ tab, float* __restrict__ sw_t,
    float* __restrict__ Z) {
  constexpr int K = 2048;
  constexpr int NT = K / 64;               // 32 K-tiles
  __shared__ unsigned short Ls[4 * 16384 + 2 * 1024];

  const int tid = threadIdx.x;
  const int lane = tid & 63, wave = tid >> 6;
  const int wr = wave >> 2, wc = wave & 3;           // 2 x 4 waves
  const int l15 = lane & 15, lk = lane >> 4, l7 = lane & 7;

  // XCD swizzle (bijective, 256 wgs / 8 XCDs)
  const int orig = blockIdx.x;
  const int wgid = (orig & 7) * 32 + (orig >> 3);
  const int bm = wgid >> 2;                          // 0..63
  const int bn = wgid & 3;                           // 0..3
  const int b  = bm >> 3;

  // ---- staging source (pre-swizzled: chunk = (tid&7) ^ (row&7)) -----------
  const int srow = tid >> 3;                         // 0..63 (pass stride 64)
  const int scb  = (tid & 7) ^ (srow & 7);
  const unsigned short* Asrc = A + ((size_t)(bm * 256 + srow)) * K + scb * 8;
  const unsigned short* Bsrc = W + ((size_t)(bn * 256 + srow)) * K + scb * 8;
  const int crow = (lane >> 3) & 3;                  // 0..3
  const int ccb  = (lane & 7) ^ (crow & 7);
  const unsigned short* Csrc =
      Cpad + ((size_t)(b * 128 + bn * 4 + crow)) * K + ccb * 8;
  const int wave512 = wave * 512;
  unsigned short* Lc = Ls + 65536;

  // ---- accumulators -------------------------------------------------------
  f32x4 acc[8][4];
  f32x4 accc[8];
#pragma unroll
  for (int i = 0; i < 8; ++i) {
    accc[i] = (f32x4){0.f, 0.f, 0.f, 0.f};
#pragma unroll
    for (int j = 0; j < 4; ++j) acc[i][j] = (f32x4){0.f, 0.f, 0.f, 0.f};
  }

  // ---- LDS read bases (shorts), row stride 64 -----------------------------
  int rowA[8], rowB[4];
#pragma unroll
  for (int mi = 0; mi < 8; ++mi) rowA[mi] = (wr * 128 + mi * 16 + l15) * 64;
#pragma unroll
  for (int nj = 0; nj < 4; ++nj) rowB[nj] = (wc * 64 + nj * 16 + l15) * 64;
  const int rowC = l15 * 64;

  // ---- prologue: stage tiles 0 -> buf0, 1 -> buf1 (C after A/B: 9th load) --
#pragma unroll
  for (int p = 0; p < 4; ++p) {
    gld16(Asrc + (size_t)p * 64 * K, Ls + p * 4096 + wave512);
    gld16(Bsrc + (size_t)p * 64 * K, Ls + 16384 + p * 4096 + wave512);
  }
  if (wave == 0 && lane < 32) gld16(Csrc, Lc);
#pragma unroll
  for (int p = 0; p < 4; ++p) {
    gld16(Asrc + (size_t)p * 64 * K + 64, Ls + 32768 + p * 4096 + wave512);
    gld16(Bsrc + (size_t)p * 64 * K + 64, Ls + 49152 + p * 4096 + wave512);
  }
  if (wave == 0 && lane < 32) gld16(Csrc + 64, Lc + 1024);
  if (wave == 0) { VM9(); } else { VM8(); }
  SBAR();

  // ---- main loop ----------------------------------------------------------
  for (int t = 0; t < NT; ++t) {
    const unsigned short* bufA = Ls + (t & 1) * 32768;
    const unsigned short* bufB = bufA + 16384;
    const unsigned short* bufC = Lc + (t & 1) * 1024;
#pragma unroll
    for (int ks = 0; ks < 2; ++ks) {
      const int offk = ((((ks << 2) | lk) ^ l7) << 3);  // swizzled, shorts
      bf16x8 af[8], bfr[4], cf;
#pragma unroll
      for (int mi = 0; mi < 8; ++mi)
        af[mi] = *(const bf16x8*)(bufA + rowA[mi] + offk);
#pragma unroll
      for (int nj = 0; nj < 4; ++nj)
        bfr[nj] = *(const bf16x8*)(bufB + rowB[nj] + offk);
      cf = *(const bf16x8*)(bufC + rowC + offk);
      __builtin_amdgcn_s_setprio(1);
#pragma unroll
      for (int mi = 0; mi < 8; ++mi) {
        accc[mi] = __builtin_amdgcn_mfma_f32_16x16x32_bf16(af[mi], cf,
                                                           accc[mi], 0, 0, 0);
#pragma unroll
        for (int nj = 0; nj < 4; ++nj)
          acc[mi][nj] = __builtin_amdgcn_mfma_f32_16x16x32_bf16(
              af[mi], bfr[nj], acc[mi][nj], 0, 0, 0);
      }
      __builtin_amdgcn_s_setprio(0);
    }
    if (t == NT - 1) break;
    SBAR();                                  // all waves done reading buf[t&1]
    if (t + 2 < NT) {
      const int k0 = (t + 2) * 64;
      unsigned short* dA = Ls + (t & 1) * 32768 + wave512;
      unsigned short* dB = dA + 16384;
#pragma unroll
      for (int p = 0; p < 4; ++p) {
        gld16(Asrc + (size_t)p * 64 * K + k0, dA + p * 4096);
        gld16(Bsrc + (size_t)p * 64 * K + k0, dB + p * 4096);
      }
      if (wave == 0 && lane < 32) gld16(Csrc + k0, Lc + (t & 1) * 1024);
      if (wave == 0) { VM9(); } else { VM8(); }   // t+1 landed; t+2 in flight
    } else {
      VM0();                                 // last tile (t+1=NT-1) landed
    }
    SBAR();                                  // tile t+1 visible to all waves
  }

  // ---- epilogue: rot score for head h = bn*4+wc, rows wr*128..+128 --------
  const int h  = bn * 4 + wc;
  const int rg = lk;                          // lane>>4
  const float* qb  = qv + ((size_t)b * 16 + h) * 128;
  const float* kbh = kb + h * 128;
  const float qkbv = qkb[b * 16 + h];
  float rowsum[8][4];
#pragma unroll
  for (int mi = 0; mi < 8; ++mi)
#pragma unroll
    for (int r = 0; r < 4; ++r) rowsum[mi][r] = 0.f;

  const int s0g = bm * 256 + wr * 128;        // global row base for this wave
  const float sgn = (l15 & 1) ? -1.f : 1.f;
#pragma unroll
  for (int nj = 0; nj < 4; ++nj) {
    const int c = nj * 16 + l15;
    const float qd   = qb[c];
    const float qps  = sgn * qb[c ^ 1];
    const float bias = kbh[c];
    const int i = c >> 1;
#pragma unroll
    for (int mi = 0; mi < 8; ++mi)
#pragma unroll
      for (int r = 0; r < 4; ++r) {
        const int t = s0g + mi * 16 + rg * 4 + r;
        const float2 sc = tab[(t & 2047) * 32 + i];
        rowsum[mi][r] += (acc[mi][nj][r] + bias) * (qd * sc.y + qps * sc.x);
      }
  }
#pragma unroll
  for (int mi = 0; mi < 8; ++mi)
#pragma unroll
    for (int r = 0; r < 4; ++r) {
      float v = rowsum[mi][r];
      v += __shfl_xor(v, 1);
      v += __shfl_xor(v, 2);
      v += __shfl_xor(v, 4);
      v += __shfl_xor(v, 8);
      rowsum[mi][r] = v;
    }
  // add plain score (col wc of accc, fetched from lane (lane&48)|wc) + bias.
  const int srcl = (lane & 48) | wc;
#pragma unroll
  for (int mi = 0; mi < 8; ++mi)
#pragma unroll
    for (int r = 0; r < 4; ++r)
      rowsum[mi][r] += __shfl(accc[mi][r], srcl) + qkbv;

  float zpart = 0.f;
  if (l15 == 0) {   // lanes 0,16,32,48 hold full sums for 32 rows each
#pragma unroll
    for (int mi = 0; mi < 8; ++mi)
#pragma unroll
      for (int r = 0; r < 4; ++r) {
        const int gr = s0g + mi * 16 + rg * 4 + r;     // global row 0..16383
        const float w = __expf(rowsum[mi][r] - 40.f);
        sw_t[(size_t)gr * 16 + h] = w;
        zpart += w;
      }
    zpart += __shfl_xor(zpart, 16);
    zpart += __shfl_xor(zpart, 32);
    if (lane == 0) atomicAdd(&Z[b * 16 + h], zpart);
  }
}

// ---------------------------------------------------------------------------
// 4. attn_wsum: wsumN[b,h,e] += sum_{t in chunk} w[b,t,h]*hs[b,t,e] (atomic).
//    grid (8 b, 4 ech, 8 tc), 256-token chunks; comb kernel deleted.
// ---------------------------------------------------------------------------
__global__ __launch_bounds__(256) void attn_wsum_kernel(
    const unsigned short* __restrict__ hs, const float* __restrict__ sw_t,
    float* __restrict__ wsumN) {
  const int b = blockIdx.x, ech = blockIdx.y, tc = blockIdx.z;
  const int tid = threadIdx.x;
  const int e = ech * 512 + tid * 2;
  __shared__ float sw[256 * 16];
  {
    const float4* src = (const float4*)(sw_t + ((size_t)b * 2048 + tc * 256) * 16);
    float4* dst = (float4*)sw;
#pragma unroll
    for (int i = 0; i < 4; ++i) dst[tid + i * 256] = src[tid + i * 256];
  }
  __syncthreads();
  float a0[16], a1[16];
#pragma unroll
  for (int h = 0; h < 16; ++h) { a0[h] = 0.f; a1[h] = 0.f; }
  const unsigned short* hp = hs + ((size_t)b * 2048 + tc * 256) * 2048 + e;
#pragma unroll 2
  for (int tt = 0; tt < 256; ++tt) {
    const unsigned hv = *(const unsigned*)(hp + (size_t)tt * 2048);
    const float h0 = __uint_as_float(hv << 16);
    const float h1 = __uint_as_float(hv & 0xffff0000u);
    const float4 w0 = *(const float4*)(sw + tt * 16 + 0);
    const float4 w1 = *(const float4*)(sw + tt * 16 + 4);
    const float4 w2 = *(const float4*)(sw + tt * 16 + 8);
    const float4 w3 = *(const float4*)(sw + tt * 16 + 12);
    const float wv[16] = {w0.x, w0.y, w0.z, w0.w, w1.x, w1.y, w1.z, w1.w,
                          w2.x, w2.y, w2.z, w2.w, w3.x, w3.y, w3.z, w3.w};
#pragma unroll
    for (int h = 0; h < 16; ++h) {
      a0[h] += wv[h] * h0;
      a1[h] += wv[h] * h1;
    }
  }
#pragma unroll
  for (int h = 0; h < 16; ++h) {
    float* dst = wsumN + ((size_t)b * 16 + h) * 2048 + e;
    atomicAdd(dst, a0[h]);
    atomicAdd(dst + 1, a1[h]);
  }
}

// ---------------------------------------------------------------------------
// 6. attn_vgemv: aout[bh][d] = (v_w[h*128+d] . wsumN[bh]) / Z[bh] + v_b
// ---------------------------------------------------------------------------
__global__ __launch_bounds__(256) void attn_vgemv_kernel(
    const float* __restrict__ vw, const float* __restrict__ vb,
    const float* __restrict__ wsumN, const float* __restrict__ Z,
    float* __restrict__ aout) {
  const int tid = threadIdx.x, lane = tid & 63, wave = tid >> 6;
  const int gw = blockIdx.x * 4 + wave;
  const int h = gw >> 7, d = gw & 127;
  const float* vr = vw + (size_t)gw * 2048;
  float p[8] = {0, 0, 0, 0, 0, 0, 0, 0};
#pragma unroll
  for (int it = 0; it < 8; ++it) {
    const int k = it * 256 + lane * 4;
    float4 wv = *(const float4*)(vr + k);
#pragma unroll
    for (int b = 0; b < 8; ++b) {
      float4 xv = *(const float4*)(wsumN + ((size_t)b * 16 + h) * 2048 + k);
      p[b] += wv.x * xv.x + wv.y * xv.y + wv.z * xv.z + wv.w * xv.w;
    }
  }
#pragma unroll
  for (int b = 0; b < 8; ++b)
    for (int m = 1; m < 64; m <<= 1) p[b] += __shfl_xor(p[b], m);
  if (lane == 0) {
    const float bb = vb[gw];
#pragma unroll
    for (int b = 0; b < 8; ++b)
      aout[((size_t)b * 16 + h) * 128 + d] = p[b] / Z[b * 16 + h] + bb;
  }
}

// ---------------------------------------------------------------------------
extern "C" void kernel_launch(void* const* d_in, const int* in_sizes, int n_in,
                              void* d_out, int out_size, void* d_ws, size_t ws_size,
                              hipStream_t stream) {
  (void)in_sizes; (void)n_in; (void)out_size; (void)ws_size;
  const float* hidden = (const float*)d_in[0];
  const int*   ids    = (const int*)d_in[1];
  const float* ln_w   = (const float*)d_in[2];
  const float* ln_b   = (const float*)d_in[3];
  const float* q_w    = (const float*)d_in[4];
  const float* q_b    = (const float*)d_in[5];
  const float* k_w    = (const float*)d_in[6];
  const float* k_b    = (const float*)d_in[7];
  const float* v_w    = (const float*)d_in[8];
  const float* v_b    = (const float*)d_in[9];
  const float* out_w  = (const float*)d_in[10];
  const float* out_b  = (const float*)d_in[11];
  float* out = (float*)d_out;

  char* ws = (char*)d_ws;
  unsigned short* hs  = (unsigned short*)ws; ws += (size_t)16384 * 2048 * 2;  // 64 MB
  unsigned short* Wk  = (unsigned short*)ws; ws += (size_t)1024 * 2048 * 2;   // 4 MB (rot)
  unsigned short* Cpad = (unsigned short*)ws; ws += (size_t)8 * 128 * 2048 * 2; // 4 MB
  float2* sctab = (float2*)ws; ws += (size_t)2048 * 32 * 8;                   // 512 KB
  float* qv     = (float*)ws; ws += (size_t)8 * 2048 * 4;
  float* hl     = (float*)ws; ws += (size_t)8 * 2048 * 4;
  float* aout   = (float*)ws; ws += (size_t)8 * 2048 * 4;
  float* sw_t   = (float*)ws; ws += (size_t)8 * 2048 * 16 * 4;                // 1 MB
  float* qkb    = (float*)ws; ws += 128 * 4;
  float* Zb     = (float*)ws; ws += 128 * 4;
  float* wsumN  = (float*)ws; ws += (size_t)128 * 2048 * 4;                   // 1 MB

  prep_kernel<<<18952, 256, 0, stream>>>(hidden, ids, ln_w, ln_b, k_w,
                                         hs, Wk, sctab, hl, Zb, wsumN);
  qhead_kernel<<<128, 256, 0, stream>>>(hl, q_w, q_b, k_w, k_b,
                                        qv, Cpad, qkb);
  gemm_kscore_rot_kernel<<<256, 512, 0, stream>>>(hs, Wk, Cpad, qkb, k_b, qv,
                                                  sctab, sw_t, Zb);
  attn_wsum_kernel<<<dim3(8, 4, 8), 256, 0, stream>>>(hs, sw_t, wsumN);
  attn_vgemv_kernel<<<512, 256, 0, stream>>>(v_w, v_b, wsumN, Zb, aout);
  gemv8_kernel<<<512, 256, 0, stream>>>(aout, out_w, out_b, out);
}

// Round 6
// 419.160 us; speedup vs baseline: 1.1320x; 1.1320x over previous
//
#include <hip/hip_runtime.h>
#include <hip/hip_bf16.h>
#include <cstdint>
#include <cstddef>

// ---------------------------------------------------------------------------
// NostARHeadAttention: LN -> {Q(last), K} proj -> RoPE(K) -> 1-query attn
// with V-elimination.
// R8: rot GEMM 256^2/BK=64/8-wave dbuf, counted vmcnt, XOR-swizzle. 441.5 us.
// R9: plain GEMM fused into rot GEMM as C-subtile. 401.2 us.
// R10: qhead fusion (serial per-thread dot, 0.5 blk/CU) REGRESSED to 474.5;
//      atomic-wsum kept comb deleted.
// R11: revert qhead -> gemv8(q) + fold_c (wave-parallel, known-fast). KEEP
//      atomic wsum (comb + 16MB part stay deleted) but back to (8,4,16)
//      128-token grid for 2 blk/CU. Isolates the R10 regression.
// ---------------------------------------------------------------------------

using bf16x8 = __attribute__((ext_vector_type(8))) __bf16;
using f32x4  = __attribute__((ext_vector_type(4))) float;

__device__ __forceinline__ unsigned short f2bf(float f) {
  unsigned u = __float_as_uint(f);
  u += 0x7fffu + ((u >> 16) & 1u);   // RNE
  return (unsigned short)(u >> 16);
}

__device__ __forceinline__ void gld16(const void* g, void* l) {
  __builtin_amdgcn_global_load_lds((__attribute__((address_space(1))) void*)g,
                                   (__attribute__((address_space(3))) void*)l,
                                   16, 0, 0);
}

#define FENCE() asm volatile("" ::: "memory")
#define SBAR()  { FENCE(); __builtin_amdgcn_s_barrier(); FENCE(); }
#define VM9()   asm volatile("s_waitcnt vmcnt(9)" ::: "memory")
#define VM8()   asm volatile("s_waitcnt vmcnt(8)" ::: "memory")
#define VM0()   asm volatile("s_waitcnt vmcnt(0)" ::: "memory")

// ---------------------------------------------------------------------------
// 1. prep: fused ln (0..16383) + rot-only k_w f2bf (16384..18431) +
//    sctab (18432..18687) + ix+hlast+Z-zero (18688..18695) +
//    wsumN zero (18696..18951).
// ---------------------------------------------------------------------------
__global__ __launch_bounds__(256) void prep_kernel(
    const float* __restrict__ hidden, const int* __restrict__ ids,
    const float* __restrict__ gw, const float* __restrict__ gb,
    const float* __restrict__ kw, unsigned short* __restrict__ hs,
    unsigned short* __restrict__ Wk, float2* __restrict__ tab,
    float* __restrict__ hl, float* __restrict__ Z,
    float* __restrict__ wsumN) {
  const int blk = blockIdx.x, tid = threadIdx.x;
  const int wave = tid >> 6, lane = tid & 63;

  if (blk < 16384) {                       // ---- LayerNorm row -> bf16
    const size_t row = blk;
    const float* xr = hidden + row * 2048;
    float4 a = ((const float4*)xr)[tid];
    float4 b = ((const float4*)xr)[tid + 256];
    float s  = a.x + a.y + a.z + a.w + b.x + b.y + b.z + b.w;
    float ss = a.x*a.x + a.y*a.y + a.z*a.z + a.w*a.w +
               b.x*b.x + b.y*b.y + b.z*b.z + b.w*b.w;
    for (int m = 1; m < 64; m <<= 1) { s += __shfl_xor(s, m); ss += __shfl_xor(ss, m); }
    __shared__ float rs[4], rss[4];
    if (lane == 0) { rs[wave] = s; rss[wave] = ss; }
    __syncthreads();
    s  = rs[0] + rs[1] + rs[2] + rs[3];
    ss = rss[0] + rss[1] + rss[2] + rss[3];
    const float mu = s * (1.f / 2048.f);
    const float var = ss * (1.f / 2048.f) - mu * mu;
    const float r = rsqrtf(var + 1e-5f);
    const int i0 = tid * 4, i1 = 1024 + tid * 4;
    ushort4 p0 = {f2bf((a.x - mu) * r * gw[i0 + 0] + gb[i0 + 0]),
                  f2bf((a.y - mu) * r * gw[i0 + 1] + gb[i0 + 1]),
                  f2bf((a.z - mu) * r * gw[i0 + 2] + gb[i0 + 2]),
                  f2bf((a.w - mu) * r * gw[i0 + 3] + gb[i0 + 3])};
    ushort4 p1 = {f2bf((b.x - mu) * r * gw[i1 + 0] + gb[i1 + 0]),
                  f2bf((b.y - mu) * r * gw[i1 + 1] + gb[i1 + 1]),
                  f2bf((b.z - mu) * r * gw[i1 + 2] + gb[i1 + 2]),
                  f2bf((b.w - mu) * r * gw[i1 + 3] + gb[i1 + 3])};
    *(ushort4*)(hs + row * 2048 + i0) = p0;
    *(ushort4*)(hs + row * 2048 + i1) = p1;
  } else if (blk < 18432) {                // ---- rot cols of k_w -> bf16
    // Wk row r (0..1023) <- k_w row (r>>6)*128 + (r&63)  (head-major, 64/head)
    const size_t i4 = (size_t)(blk - 16384) * 256 + tid;   // 16B units
    const int r = (int)(i4 >> 9);
    const int col4 = (int)(i4 & 511);
    const size_t src4 = ((size_t)((r >> 6) * 128 + (r & 63))) * 512 + col4;
    float4 v = ((const float4*)kw)[src4];
    ushort4 o = {f2bf(v.x), f2bf(v.y), f2bf(v.z), f2bf(v.w)};
    ((ushort4*)Wk)[i4] = o;
  } else if (blk < 18688) {                // ---- sin/cos table (8 t / block)
    const int t = (blk - 18432) * 8 + (tid >> 5);
    const int i = tid & 31;
    const float inv = exp2f(-(float)i * (13.287712379549449f / 32.f));
    const float ang = (float)t * inv;
    tab[t * 32 + i] = make_float2(sinf(ang), cosf(ang));
  } else if (blk < 18696) {                // ---- last-token index + LN + Z=0
    const int b = blk - 18688;
    if (tid < 16) Z[b * 16 + tid] = 0.f;
    int best = -1;
    for (int t = tid; t < 2048; t += 256)
      if (ids[b * 2048 + t] != 50257) best = (t > best) ? t : best;
    for (int m = 1; m < 64; m <<= 1) {
      int o = __shfl_xor(best, m);
      best = (o > best) ? o : best;
    }
    __shared__ int rb[4];
    if (lane == 0) rb[wave] = best;
    __syncthreads();
    int ix = rb[0];
    for (int w = 1; w < 4; ++w) ix = (rb[w] > ix) ? rb[w] : ix;
    ix = (ix < 0) ? 0 : ix;
    const float* xr = hidden + ((size_t)b * 2048 + ix) * 2048;
    float4 a = ((const float4*)xr)[tid];
    float4 c = ((const float4*)xr)[tid + 256];
    float s  = a.x + a.y + a.z + a.w + c.x + c.y + c.z + c.w;
    float ss = a.x*a.x + a.y*a.y + a.z*a.z + a.w*a.w +
               c.x*c.x + c.y*c.y + c.z*c.z + c.w*c.w;
    for (int m = 1; m < 64; m <<= 1) { s += __shfl_xor(s, m); ss += __shfl_xor(ss, m); }
    __shared__ float rs2[4], rss2[4];
    if (lane == 0) { rs2[wave] = s; rss2[wave] = ss; }
    __syncthreads();
    s  = rs2[0] + rs2[1] + rs2[2] + rs2[3];
    ss = rss2[0] + rss2[1] + rss2[2] + rss2[3];
    const float mu = s * (1.f / 2048.f);
    const float var = ss * (1.f / 2048.f) - mu * mu;
    const float r = rsqrtf(var + 1e-5f);
    const int i0 = tid * 4, i1 = 1024 + tid * 4;
    float* yo = hl + (size_t)b * 2048;
    yo[i0 + 0] = (a.x - mu) * r * gw[i0 + 0] + gb[i0 + 0];
    yo[i0 + 1] = (a.y - mu) * r * gw[i0 + 1] + gb[i0 + 1];
    yo[i0 + 2] = (a.z - mu) * r * gw[i0 + 2] + gb[i0 + 2];
    yo[i0 + 3] = (a.w - mu) * r * gw[i0 + 3] + gb[i0 + 3];
    yo[i1 + 0] = (c.x - mu) * r * gw[i1 + 0] + gb[i1 + 0];
    yo[i1 + 1] = (c.y - mu) * r * gw[i1 + 1] + gb[i1 + 1];
    yo[i1 + 2] = (c.z - mu) * r * gw[i1 + 2] + gb[i1 + 2];
    yo[i1 + 3] = (c.w - mu) * r * gw[i1 + 3] + gb[i1 + 3];
  } else {                                 // ---- zero wsumN (1 MB)
    const int idx = (blk - 18696) * 256 + tid;
    ((float4*)wsumN)[idx] = (float4){0.f, 0.f, 0.f, 0.f};
  }
}

// ---------------------------------------------------------------------------
// 2. GEMV: Y[8][2048] = X[8][2048] @ W^T + bias (fp32), 512 blocks.
// ---------------------------------------------------------------------------
__global__ __launch_bounds__(256) void gemv8_kernel(const float* __restrict__ X,
                                                    const float* __restrict__ W,
                                                    const float* __restrict__ bias,
                                                    float* __restrict__ Y) {
  const int tid = threadIdx.x, lane = tid & 63, wave = tid >> 6;
  const int e = blockIdx.x * 4 + wave;
  const float* wr = W + (size_t)e * 2048;
  float p[8] = {0, 0, 0, 0, 0, 0, 0, 0};
#pragma unroll
  for (int it = 0; it < 8; ++it) {
    const int k = it * 256 + lane * 4;
    float4 wv = *(const float4*)(wr + k);
#pragma unroll
    for (int b = 0; b < 8; ++b) {
      float4 xv = *(const float4*)(X + b * 2048 + k);
      p[b] += wv.x * xv.x + wv.y * xv.y + wv.z * xv.z + wv.w * xv.w;
    }
  }
#pragma unroll
  for (int b = 0; b < 8; ++b)
    for (int m = 1; m < 64; m <<= 1) p[b] += __shfl_xor(p[b], m);
  if (lane == 0) {
    const float bb = bias[e];
#pragma unroll
    for (int b = 0; b < 8; ++b) Y[(size_t)b * 2048 + e] = p[b] + bb;
  }
}

// ---------------------------------------------------------------------------
// 2b. fold_c: C[b,h,e] = sum_{c=64..127} q[b,h*128+c] * k_w[h*128+c, e]
//     -> Cpad rows 0..15 per b (bf16), plus qkb[b,h] = sum kb*q (plain bias).
// ---------------------------------------------------------------------------
__global__ __launch_bounds__(256) void fold_c_kernel(
    const float* __restrict__ qv, const float* __restrict__ kw,
    const float* __restrict__ kb, unsigned short* __restrict__ Cpad,
    float* __restrict__ qkb) {
  const int bh = blockIdx.x, b = bh >> 4, h = bh & 15;
  const int tid = threadIdx.x;
  const float* qh = qv + ((size_t)b * 16 + h) * 128 + 64;
  const int e0 = tid * 8;
  float acc[8] = {0, 0, 0, 0, 0, 0, 0, 0};
  for (int c = 0; c < 64; ++c) {
    const float qc = qh[c];
    const float* row = kw + ((size_t)(h * 128 + 64 + c)) * 2048 + e0;
    float4 v0 = *(const float4*)(row);
    float4 v1 = *(const float4*)(row + 4);
    acc[0] += qc * v0.x; acc[1] += qc * v0.y; acc[2] += qc * v0.z; acc[3] += qc * v0.w;
    acc[4] += qc * v1.x; acc[5] += qc * v1.y; acc[6] += qc * v1.z; acc[7] += qc * v1.w;
  }
  unsigned short* dst = Cpad + ((size_t)b * 128 + h) * 2048 + e0;
  ushort4 o0 = {f2bf(acc[0]), f2bf(acc[1]), f2bf(acc[2]), f2bf(acc[3])};
  ushort4 o1 = {f2bf(acc[4]), f2bf(acc[5]), f2bf(acc[6]), f2bf(acc[7])};
  *(ushort4*)(dst) = o0;
  *(ushort4*)(dst + 4) = o1;
  if (tid < 64) {
    float p = kb[h * 128 + 64 + tid] * qh[tid];
    for (int m = 1; m < 64; m <<= 1) p += __shfl_xor(p, m);
    if (tid == 0) qkb[bh] = p;
  }
}

// ---------------------------------------------------------------------------
// 3. gemm_kscore_rot: 256^2 tile, BK=64, 8 waves (2Mx4N), double-buffered
//    LDS, counted vmcnt, XOR-swizzled LDS reads (pre-swizzled gld src).
//    FUSED plain score: 16-row C-subtile (4 valid rows = this block's heads)
//    staged by wave0 -> +8 MFMA/ks into accc.  Epilogue: rot dot with rotated
//    q + kb, + shfl'd plain col + qkb, exp(sc-40) -> sw_t, Z atomicAdd.
// ---------------------------------------------------------------------------
__global__ __launch_bounds__(512, 2) void gemm_kscore_rot_kernel(
    const unsigned short* __restrict__ A, const unsigned short* __restrict__ W,
    const unsigned short* __restrict__ Cpad, const float* __restrict__ qkb,
    const float* __restrict__ kb, const float* __restrict__ qv,
    const float2* __restrict__ tab, float* __restrict__ sw_t,
    float* __restrict__ Z) {
  constexpr int K = 2048;
  constexpr int NT = K / 64;               // 32 K-tiles
  __shared__ unsigned short Ls[4 * 16384 + 2 * 1024];

  const int tid = threadIdx.x;
  const int lane = tid & 63, wave = tid >> 6;
  const int wr = wave >> 2, wc = wave & 3;           // 2 x 4 waves
  const int l15 = lane & 15, lk = lane >> 4, l7 = lane & 7;

  // XCD swizzle (bijective, 256 wgs / 8 XCDs)
  const int orig = blockIdx.x;
  const int wgid = (orig & 7) * 32 + (orig >> 3);
  const int bm = wgid >> 2;                          // 0..63
  const int bn = wgid & 3;                           // 0..3
  const int b  = bm >> 3;

  // ---- staging source (pre-swizzled: chunk = (tid&7) ^ (row&7)) -----------
  const int srow = tid >> 3;                         // 0..63 (pass stride 64)
  const int scb  = (tid & 7) ^ (srow & 7);
  const unsigned short* Asrc = A + ((size_t)(bm * 256 + srow)) * K + scb * 8;
  const unsigned short* Bsrc = W + ((size_t)(bn * 256 + srow)) * K + scb * 8;
  const int crow = (lane >> 3) & 3;                  // 0..3
  const int ccb  = (lane & 7) ^ (crow & 7);
  const unsigned short* Csrc =
      Cpad + ((size_t)(b * 128 + bn * 4 + crow)) * K + ccb * 8;
  const int wave512 = wave * 512;
  unsigned short* Lc = Ls + 65536;

  // ---- accumulators -------------------------------------------------------
  f32x4 acc[8][4];
  f32x4 accc[8];
#pragma unroll
  for (int i = 0; i < 8; ++i) {
    accc[i] = (f32x4){0.f, 0.f, 0.f, 0.f};
#pragma unroll
    for (int j = 0; j < 4; ++j) acc[i][j] = (f32x4){0.f, 0.f, 0.f, 0.f};
  }

  // ---- LDS read bases (shorts), row stride 64 -----------------------------
  int rowA[8], rowB[4];
#pragma unroll
  for (int mi = 0; mi < 8; ++mi) rowA[mi] = (wr * 128 + mi * 16 + l15) * 64;
#pragma unroll
  for (int nj = 0; nj < 4; ++nj) rowB[nj] = (wc * 64 + nj * 16 + l15) * 64;
  const int rowC = l15 * 64;

  // ---- prologue: stage tiles 0 -> buf0, 1 -> buf1 (C after A/B: 9th load) --
#pragma unroll
  for (int p = 0; p < 4; ++p) {
    gld16(Asrc + (size_t)p * 64 * K, Ls + p * 4096 + wave512);
    gld16(Bsrc + (size_t)p * 64 * K, Ls + 16384 + p * 4096 + wave512);
  }
  if (wave == 0 && lane < 32) gld16(Csrc, Lc);
#pragma unroll
  for (int p = 0; p < 4; ++p) {
    gld16(Asrc + (size_t)p * 64 * K + 64, Ls + 32768 + p * 4096 + wave512);
    gld16(Bsrc + (size_t)p * 64 * K + 64, Ls + 49152 + p * 4096 + wave512);
  }
  if (wave == 0 && lane < 32) gld16(Csrc + 64, Lc + 1024);
  if (wave == 0) { VM9(); } else { VM8(); }
  SBAR();

  // ---- main loop ----------------------------------------------------------
  for (int t = 0; t < NT; ++t) {
    const unsigned short* bufA = Ls + (t & 1) * 32768;
    const unsigned short* bufB = bufA + 16384;
    const unsigned short* bufC = Lc + (t & 1) * 1024;
#pragma unroll
    for (int ks = 0; ks < 2; ++ks) {
      const int offk = ((((ks << 2) | lk) ^ l7) << 3);  // swizzled, shorts
      bf16x8 af[8], bfr[4], cf;
#pragma unroll
      for (int mi = 0; mi < 8; ++mi)
        af[mi] = *(const bf16x8*)(bufA + rowA[mi] + offk);
#pragma unroll
      for (int nj = 0; nj < 4; ++nj)
        bfr[nj] = *(const bf16x8*)(bufB + rowB[nj] + offk);
      cf = *(const bf16x8*)(bufC + rowC + offk);
      __builtin_amdgcn_s_setprio(1);
#pragma unroll
      for (int mi = 0; mi < 8; ++mi) {
        accc[mi] = __builtin_amdgcn_mfma_f32_16x16x32_bf16(af[mi], cf,
                                                           accc[mi], 0, 0, 0);
#pragma unroll
        for (int nj = 0; nj < 4; ++nj)
          acc[mi][nj] = __builtin_amdgcn_mfma_f32_16x16x32_bf16(
              af[mi], bfr[nj], acc[mi][nj], 0, 0, 0);
      }
      __builtin_amdgcn_s_setprio(0);
    }
    if (t == NT - 1) break;
    SBAR();                                  // all waves done reading buf[t&1]
    if (t + 2 < NT) {
      const int k0 = (t + 2) * 64;
      unsigned short* dA = Ls + (t & 1) * 32768 + wave512;
      unsigned short* dB = dA + 16384;
#pragma unroll
      for (int p = 0; p < 4; ++p) {
        gld16(Asrc + (size_t)p * 64 * K + k0, dA + p * 4096);
        gld16(Bsrc + (size_t)p * 64 * K + k0, dB + p * 4096);
      }
      if (wave == 0 && lane < 32) gld16(Csrc + k0, Lc + (t & 1) * 1024);
      if (wave == 0) { VM9(); } else { VM8(); }   // t+1 landed; t+2 in flight
    } else {
      VM0();                                 // last tile (t+1=NT-1) landed
    }
    SBAR();                                  // tile t+1 visible to all waves
  }

  // ---- epilogue: rot score for head h = bn*4+wc, rows wr*128..+128 --------
  const int h  = bn * 4 + wc;
  const int rg = lk;                          // lane>>4
  const float* qb  = qv + ((size_t)b * 16 + h) * 128;
  const float* kbh = kb + h * 128;
  const float qkbv = qkb[b * 16 + h];
  float rowsum[8][4];
#pragma unroll
  for (int mi = 0; mi < 8; ++mi)
#pragma unroll
    for (int r = 0; r < 4; ++r) rowsum[mi][r] = 0.f;

  const int s0g = bm * 256 + wr * 128;        // global row base for this wave
  const float sgn = (l15 & 1) ? -1.f : 1.f;
#pragma unroll
  for (int nj = 0; nj < 4; ++nj) {
    const int c = nj * 16 + l15;
    const float qd   = qb[c];
    const float qps  = sgn * qb[c ^ 1];
    const float bias = kbh[c];
    const int i = c >> 1;
#pragma unroll
    for (int mi = 0; mi < 8; ++mi)
#pragma unroll
      for (int r = 0; r < 4; ++r) {
        const int t = s0g + mi * 16 + rg * 4 + r;
        const float2 sc = tab[(t & 2047) * 32 + i];
        rowsum[mi][r] += (acc[mi][nj][r] + bias) * (qd * sc.y + qps * sc.x);
      }
  }
#pragma unroll
  for (int mi = 0; mi < 8; ++mi)
#pragma unroll
    for (int r = 0; r < 4; ++r) {
      float v = rowsum[mi][r];
      v += __shfl_xor(v, 1);
      v += __shfl_xor(v, 2);
      v += __shfl_xor(v, 4);
      v += __shfl_xor(v, 8);
      rowsum[mi][r] = v;
    }
  // add plain score (col wc of accc, fetched from lane (lane&48)|wc) + bias.
  const int srcl = (lane & 48) | wc;
#pragma unroll
  for (int mi = 0; mi < 8; ++mi)
#pragma unroll
    for (int r = 0; r < 4; ++r)
      rowsum[mi][r] += __shfl(accc[mi][r], srcl) + qkbv;

  float zpart = 0.f;
  if (l15 == 0) {   // lanes 0,16,32,48 hold full sums for 32 rows each
#pragma unroll
    for (int mi = 0; mi < 8; ++mi)
#pragma unroll
      for (int r = 0; r < 4; ++r) {
        const int gr = s0g + mi * 16 + rg * 4 + r;     // global row 0..16383
        const float w = __expf(rowsum[mi][r] - 40.f);
        sw_t[(size_t)gr * 16 + h] = w;
        zpart += w;
      }
    zpart += __shfl_xor(zpart, 16);
    zpart += __shfl_xor(zpart, 32);
    if (lane == 0) atomicAdd(&Z[b * 16 + h], zpart);
  }
}

// ---------------------------------------------------------------------------
// 4. attn_wsum: wsumN[b,h,e] += sum_{t in chunk} w[b,t,h]*hs[b,t,e] (atomic).
//    grid (8 b, 4 ech, 16 tc), 128-token chunks (2 blk/CU); comb deleted.
// ---------------------------------------------------------------------------
__global__ __launch_bounds__(256) void attn_wsum_kernel(
    const unsigned short* __restrict__ hs, const float* __restrict__ sw_t,
    float* __restrict__ wsumN) {
  const int b = blockIdx.x, ech = blockIdx.y, tc = blockIdx.z;
  const int tid = threadIdx.x;
  const int e = ech * 512 + tid * 2;
  __shared__ float sw[128 * 16];
  {
    const float4* src = (const float4*)(sw_t + ((size_t)b * 2048 + tc * 128) * 16);
    float4* dst = (float4*)sw;
    dst[tid] = src[tid];
    dst[tid + 256] = src[tid + 256];
  }
  __syncthreads();
  float a0[16], a1[16];
#pragma unroll
  for (int h = 0; h < 16; ++h) { a0[h] = 0.f; a1[h] = 0.f; }
  const unsigned short* hp = hs + ((size_t)b * 2048 + tc * 128) * 2048 + e;
#pragma unroll 2
  for (int tt = 0; tt < 128; ++tt) {
    const unsigned hv = *(const unsigned*)(hp + (size_t)tt * 2048);
    const float h0 = __uint_as_float(hv << 16);
    const float h1 = __uint_as_float(hv & 0xffff0000u);
    const float4 w0 = *(const float4*)(sw + tt * 16 + 0);
    const float4 w1 = *(const float4*)(sw + tt * 16 + 4);
    const float4 w2 = *(const float4*)(sw + tt * 16 + 8);
    const float4 w3 = *(const float4*)(sw + tt * 16 + 12);
    const float wv[16] = {w0.x, w0.y, w0.z, w0.w, w1.x, w1.y, w1.z, w1.w,
                          w2.x, w2.y, w2.z, w2.w, w3.x, w3.y, w3.z, w3.w};
#pragma unroll
    for (int h = 0; h < 16; ++h) {
      a0[h] += wv[h] * h0;
      a1[h] += wv[h] * h1;
    }
  }
#pragma unroll
  for (int h = 0; h < 16; ++h) {
    float* dst = wsumN + ((size_t)b * 16 + h) * 2048 + e;
    atomicAdd(dst, a0[h]);
    atomicAdd(dst + 1, a1[h]);
  }
}

// ---------------------------------------------------------------------------
// 5. attn_vgemv: aout[bh][d] = (v_w[h*128+d] . wsumN[bh]) / Z[bh] + v_b
// ---------------------------------------------------------------------------
__global__ __launch_bounds__(256) void attn_vgemv_kernel(
    const float* __restrict__ vw, const float* __restrict__ vb,
    const float* __restrict__ wsumN, const float* __restrict__ Z,
    float* __restrict__ aout) {
  const int tid = threadIdx.x, lane = tid & 63, wave = tid >> 6;
  const int gw = blockIdx.x * 4 + wave;
  const int h = gw >> 7, d = gw & 127;
  const float* vr = vw + (size_t)gw * 2048;
  float p[8] = {0, 0, 0, 0, 0, 0, 0, 0};
#pragma unroll
  for (int it = 0; it < 8; ++it) {
    const int k = it * 256 + lane * 4;
    float4 wv = *(const float4*)(vr + k);
#pragma unroll
    for (int b = 0; b < 8; ++b) {
      float4 xv = *(const float4*)(wsumN + ((size_t)b * 16 + h) * 2048 + k);
      p[b] += wv.x * xv.x + wv.y * xv.y + wv.z * xv.z + wv.w * xv.w;
    }
  }
#pragma unroll
  for (int b = 0; b < 8; ++b)
    for (int m = 1; m < 64; m <<= 1) p[b] += __shfl_xor(p[b], m);
  if (lane == 0) {
    const float bb = vb[gw];
#pragma unroll
    for (int b = 0; b < 8; ++b)
      aout[((size_t)b * 16 + h) * 128 + d] = p[b] / Z[b * 16 + h] + bb;
  }
}

// ---------------------------------------------------------------------------
extern "C" void kernel_launch(void* const* d_in, const int* in_sizes, int n_in,
                              void* d_out, int out_size, void* d_ws, size_t ws_size,
                              hipStream_t stream) {
  (void)in_sizes; (void)n_in; (void)out_size; (void)ws_size;
  const float* hidden = (const float*)d_in[0];
  const int*   ids    = (const int*)d_in[1];
  const float* ln_w   = (const float*)d_in[2];
  const float* ln_b   = (const float*)d_in[3];
  const float* q_w    = (const float*)d_in[4];
  const float* q_b    = (const float*)d_in[5];
  const float* k_w    = (const float*)d_in[6];
  const float* k_b    = (const float*)d_in[7];
  const float* v_w    = (const float*)d_in[8];
  const float* v_b    = (const float*)d_in[9];
  const float* out_w  = (const float*)d_in[10];
  const float* out_b  = (const float*)d_in[11];
  float* out = (float*)d_out;

  char* ws = (char*)d_ws;
  unsigned short* hs  = (unsigned short*)ws; ws += (size_t)16384 * 2048 * 2;  // 64 MB
  unsigned short* Wk  = (unsigned short*)ws; ws += (size_t)1024 * 2048 * 2;   // 4 MB (rot)
  unsigned short* Cpad = (unsigned short*)ws; ws += (size_t)8 * 128 * 2048 * 2; // 4 MB
  float2* sctab = (float2*)ws; ws += (size_t)2048 * 32 * 8;                   // 512 KB
  float* qv     = (float*)ws; ws += (size_t)8 * 2048 * 4;
  float* hl     = (float*)ws; ws += (size_t)8 * 2048 * 4;
  float* aout   = (float*)ws; ws += (size_t)8 * 2048 * 4;
  float* sw_t   = (float*)ws; ws += (size_t)8 * 2048 * 16 * 4;                // 1 MB
  float* qkb    = (float*)ws; ws += 128 * 4;
  float* Zb     = (float*)ws; ws += 128 * 4;
  float* wsumN  = (float*)ws; ws += (size_t)128 * 2048 * 4;                   // 1 MB

  prep_kernel<<<18952, 256, 0, stream>>>(hidden, ids, ln_w, ln_b, k_w,
                                         hs, Wk, sctab, hl, Zb, wsumN);
  gemv8_kernel<<<512, 256, 0, stream>>>(hl, q_w, q_b, qv);
  fold_c_kernel<<<128, 256, 0, stream>>>(qv, k_w, k_b, Cpad, qkb);
  gemm_kscore_rot_kernel<<<256, 512, 0, stream>>>(hs, Wk, Cpad, qkb, k_b, qv,
                                                  sctab, sw_t, Zb);
  attn_wsum_kernel<<<dim3(8, 4, 16), 256, 0, stream>>>(hs, sw_t, wsumN);
  attn_vgemv_kernel<<<512, 256, 0, stream>>>(v_w, v_b, wsumN, Zb, aout);
  gemv8_kernel<<<512, 256, 0, stream>>>(aout, out_w, out_b, out);
}

// Round 7
// 406.275 us; speedup vs baseline: 1.1679x; 1.0317x over previous
//
#include <hip/hip_runtime.h>
#include <hip/hip_bf16.h>
#include <cstdint>
#include <cstddef>

// ---------------------------------------------------------------------------
// NostARHeadAttention: LN -> {Q(last), K} proj -> RoPE(K) -> 1-query attn
// with V-elimination.
// R8: rot GEMM 256^2/BK=64/8-wave dbuf, counted vmcnt, XOR-swizzle. 441.5 us.
// R9: plain GEMM fused into rot GEMM as C-subtile. 401.2 us (part+comb wsum).
// R10: qhead serial-dot fusion REGRESSED (474.5). R11: reverted qhead; atomic
//      wsum measured +20 vs part+comb (419.2). rot 90.6 @ MfmaUtil 39%.
// R12: (a) rot -> BK=32, TRIPLE-buffer LDS (99 KB), ONE barrier/tile: t+2
//      staging issued at top of iter (dest freed by prev end-barrier) so the
//      issue overlaps compute; steady-state vmcnt(4)/(5 w0); BK=32's 64B row
//      stride makes 16-row x 4-chunk b128 reads conflict-free WITHOUT swizzle
//      (linear staging + reads). Accumulation order bit-identical.
//      (b) wsum reverted to part+comb (atomics cost +20).
//      (c) fold_c split 128->256 blocks (half e-range each).
// ---------------------------------------------------------------------------

using bf16x8 = __attribute__((ext_vector_type(8))) __bf16;
using f32x4  = __attribute__((ext_vector_type(4))) float;

__device__ __forceinline__ unsigned short f2bf(float f) {
  unsigned u = __float_as_uint(f);
  u += 0x7fffu + ((u >> 16) & 1u);   // RNE
  return (unsigned short)(u >> 16);
}

__device__ __forceinline__ void gld16(const void* g, void* l) {
  __builtin_amdgcn_global_load_lds((__attribute__((address_space(1))) void*)g,
                                   (__attribute__((address_space(3))) void*)l,
                                   16, 0, 0);
}

#define FENCE() asm volatile("" ::: "memory")
#define SBAR()  { FENCE(); __builtin_amdgcn_s_barrier(); FENCE(); }
#define VM5()   asm volatile("s_waitcnt vmcnt(5)" ::: "memory")
#define VM4()   asm volatile("s_waitcnt vmcnt(4)" ::: "memory")
#define VM0()   asm volatile("s_waitcnt vmcnt(0)" ::: "memory")

// ---------------------------------------------------------------------------
// 1. prep: fused ln (0..16383) + rot-only k_w f2bf (16384..18431) +
//    sctab (18432..18687) + ix+hlast+Z-zero (18688..18695).
// ---------------------------------------------------------------------------
__global__ __launch_bounds__(256) void prep_kernel(
    const float* __restrict__ hidden, const int* __restrict__ ids,
    const float* __restrict__ gw, const float* __restrict__ gb,
    const float* __restrict__ kw, unsigned short* __restrict__ hs,
    unsigned short* __restrict__ Wk, float2* __restrict__ tab,
    float* __restrict__ hl, float* __restrict__ Z) {
  const int blk = blockIdx.x, tid = threadIdx.x;
  const int wave = tid >> 6, lane = tid & 63;

  if (blk < 16384) {                       // ---- LayerNorm row -> bf16
    const size_t row = blk;
    const float* xr = hidden + row * 2048;
    float4 a = ((const float4*)xr)[tid];
    float4 b = ((const float4*)xr)[tid + 256];
    float s  = a.x + a.y + a.z + a.w + b.x + b.y + b.z + b.w;
    float ss = a.x*a.x + a.y*a.y + a.z*a.z + a.w*a.w +
               b.x*b.x + b.y*b.y + b.z*b.z + b.w*b.w;
    for (int m = 1; m < 64; m <<= 1) { s += __shfl_xor(s, m); ss += __shfl_xor(ss, m); }
    __shared__ float rs[4], rss[4];
    if (lane == 0) { rs[wave] = s; rss[wave] = ss; }
    __syncthreads();
    s  = rs[0] + rs[1] + rs[2] + rs[3];
    ss = rss[0] + rss[1] + rss[2] + rss[3];
    const float mu = s * (1.f / 2048.f);
    const float var = ss * (1.f / 2048.f) - mu * mu;
    const float r = rsqrtf(var + 1e-5f);
    const int i0 = tid * 4, i1 = 1024 + tid * 4;
    ushort4 p0 = {f2bf((a.x - mu) * r * gw[i0 + 0] + gb[i0 + 0]),
                  f2bf((a.y - mu) * r * gw[i0 + 1] + gb[i0 + 1]),
                  f2bf((a.z - mu) * r * gw[i0 + 2] + gb[i0 + 2]),
                  f2bf((a.w - mu) * r * gw[i0 + 3] + gb[i0 + 3])};
    ushort4 p1 = {f2bf((b.x - mu) * r * gw[i1 + 0] + gb[i1 + 0]),
                  f2bf((b.y - mu) * r * gw[i1 + 1] + gb[i1 + 1]),
                  f2bf((b.z - mu) * r * gw[i1 + 2] + gb[i1 + 2]),
                  f2bf((b.w - mu) * r * gw[i1 + 3] + gb[i1 + 3])};
    *(ushort4*)(hs + row * 2048 + i0) = p0;
    *(ushort4*)(hs + row * 2048 + i1) = p1;
  } else if (blk < 18432) {                // ---- rot cols of k_w -> bf16
    // Wk row r (0..1023) <- k_w row (r>>6)*128 + (r&63)  (head-major, 64/head)
    const size_t i4 = (size_t)(blk - 16384) * 256 + tid;   // 16B units
    const int r = (int)(i4 >> 9);
    const int col4 = (int)(i4 & 511);
    const size_t src4 = ((size_t)((r >> 6) * 128 + (r & 63))) * 512 + col4;
    float4 v = ((const float4*)kw)[src4];
    ushort4 o = {f2bf(v.x), f2bf(v.y), f2bf(v.z), f2bf(v.w)};
    ((ushort4*)Wk)[i4] = o;
  } else if (blk < 18688) {                // ---- sin/cos table (8 t / block)
    const int t = (blk - 18432) * 8 + (tid >> 5);
    const int i = tid & 31;
    const float inv = exp2f(-(float)i * (13.287712379549449f / 32.f));
    const float ang = (float)t * inv;
    tab[t * 32 + i] = make_float2(sinf(ang), cosf(ang));
  } else {                                 // ---- last-token index + LN + Z=0
    const int b = blk - 18688;
    if (tid < 16) Z[b * 16 + tid] = 0.f;
    int best = -1;
    for (int t = tid; t < 2048; t += 256)
      if (ids[b * 2048 + t] != 50257) best = (t > best) ? t : best;
    for (int m = 1; m < 64; m <<= 1) {
      int o = __shfl_xor(best, m);
      best = (o > best) ? o : best;
    }
    __shared__ int rb[4];
    if (lane == 0) rb[wave] = best;
    __syncthreads();
    int ix = rb[0];
    for (int w = 1; w < 4; ++w) ix = (rb[w] > ix) ? rb[w] : ix;
    ix = (ix < 0) ? 0 : ix;
    const float* xr = hidden + ((size_t)b * 2048 + ix) * 2048;
    float4 a = ((const float4*)xr)[tid];
    float4 c = ((const float4*)xr)[tid + 256];
    float s  = a.x + a.y + a.z + a.w + c.x + c.y + c.z + c.w;
    float ss = a.x*a.x + a.y*a.y + a.z*a.z + a.w*a.w +
               c.x*c.x + c.y*c.y + c.z*c.z + c.w*c.w;
    for (int m = 1; m < 64; m <<= 1) { s += __shfl_xor(s, m); ss += __shfl_xor(ss, m); }
    __shared__ float rs2[4], rss2[4];
    if (lane == 0) { rs2[wave] = s; rss2[wave] = ss; }
    __syncthreads();
    s  = rs2[0] + rs2[1] + rs2[2] + rs2[3];
    ss = rss2[0] + rss2[1] + rss2[2] + rss2[3];
    const float mu = s * (1.f / 2048.f);
    const float var = ss * (1.f / 2048.f) - mu * mu;
    const float r = rsqrtf(var + 1e-5f);
    const int i0 = tid * 4, i1 = 1024 + tid * 4;
    float* yo = hl + (size_t)b * 2048;
    yo[i0 + 0] = (a.x - mu) * r * gw[i0 + 0] + gb[i0 + 0];
    yo[i0 + 1] = (a.y - mu) * r * gw[i0 + 1] + gb[i0 + 1];
    yo[i0 + 2] = (a.z - mu) * r * gw[i0 + 2] + gb[i0 + 2];
    yo[i0 + 3] = (a.w - mu) * r * gw[i0 + 3] + gb[i0 + 3];
    yo[i1 + 0] = (c.x - mu) * r * gw[i1 + 0] + gb[i1 + 0];
    yo[i1 + 1] = (c.y - mu) * r * gw[i1 + 1] + gb[i1 + 1];
    yo[i1 + 2] = (c.z - mu) * r * gw[i1 + 2] + gb[i1 + 2];
    yo[i1 + 3] = (c.w - mu) * r * gw[i1 + 3] + gb[i1 + 3];
  }
}

// ---------------------------------------------------------------------------
// 2. GEMV: Y[8][2048] = X[8][2048] @ W^T + bias (fp32), 512 blocks.
// ---------------------------------------------------------------------------
__global__ __launch_bounds__(256) void gemv8_kernel(const float* __restrict__ X,
                                                    const float* __restrict__ W,
                                                    const float* __restrict__ bias,
                                                    float* __restrict__ Y) {
  const int tid = threadIdx.x, lane = tid & 63, wave = tid >> 6;
  const int e = blockIdx.x * 4 + wave;
  const float* wr = W + (size_t)e * 2048;
  float p[8] = {0, 0, 0, 0, 0, 0, 0, 0};
#pragma unroll
  for (int it = 0; it < 8; ++it) {
    const int k = it * 256 + lane * 4;
    float4 wv = *(const float4*)(wr + k);
#pragma unroll
    for (int b = 0; b < 8; ++b) {
      float4 xv = *(const float4*)(X + b * 2048 + k);
      p[b] += wv.x * xv.x + wv.y * xv.y + wv.z * xv.z + wv.w * xv.w;
    }
  }
#pragma unroll
  for (int b = 0; b < 8; ++b)
    for (int m = 1; m < 64; m <<= 1) p[b] += __shfl_xor(p[b], m);
  if (lane == 0) {
    const float bb = bias[e];
#pragma unroll
    for (int b = 0; b < 8; ++b) Y[(size_t)b * 2048 + e] = p[b] + bb;
  }
}

// ---------------------------------------------------------------------------
// 2b. fold_c: C[b,h,e] = sum_{c=64..127} q[b,h*128+c] * k_w[h*128+c, e]
//     -> Cpad rows 0..15 per b (bf16), plus qkb[b,h] = sum kb*q.
//     256 blocks: (bh, e-half); each thread 4 e over 64 c rows.
// ---------------------------------------------------------------------------
__global__ __launch_bounds__(256) void fold_c_kernel(
    const float* __restrict__ qv, const float* __restrict__ kw,
    const float* __restrict__ kb, unsigned short* __restrict__ Cpad,
    float* __restrict__ qkb) {
  const int blk = blockIdx.x, bh = blk >> 1, half = blk & 1;
  const int b = bh >> 4, h = bh & 15;
  const int tid = threadIdx.x;
  const float* qh = qv + ((size_t)b * 16 + h) * 128 + 64;
  const int e0 = half * 1024 + tid * 4;
  float acc[4] = {0, 0, 0, 0};
#pragma unroll 4
  for (int c = 0; c < 64; ++c) {
    const float qc = qh[c];
    const float4 v = *(const float4*)(kw + ((size_t)(h * 128 + 64 + c)) * 2048 + e0);
    acc[0] += qc * v.x; acc[1] += qc * v.y; acc[2] += qc * v.z; acc[3] += qc * v.w;
  }
  ushort4 o = {f2bf(acc[0]), f2bf(acc[1]), f2bf(acc[2]), f2bf(acc[3])};
  *(ushort4*)(Cpad + ((size_t)b * 128 + h) * 2048 + e0) = o;
  if (half == 0 && tid < 64) {
    float p = kb[h * 128 + 64 + tid] * qh[tid];
    for (int m = 1; m < 64; m <<= 1) p += __shfl_xor(p, m);
    if (tid == 0) qkb[bh] = p;
  }
}

// ---------------------------------------------------------------------------
// 3. gemm_kscore_rot: 256^2 tile, BK=32, 8 waves (2Mx4N), TRIPLE-buffered
//    LDS (99 KB), ONE barrier per tile: stage t+2 at top (dest freed by prev
//    end-barrier, issue overlaps compute), vmcnt(4)/(5 w0) then barrier.
//    BK=32's 64B row stride -> b128 reads conflict-free, no swizzle.
//    FUSED plain score C-subtile (16 rows, heads duplicated x4) -> accc.
//    Epilogue: rot dot w/ rotated q + kb, + shfl'd plain col + qkb,
//    exp(sc-40) -> sw_t, Z atomicAdd.
// ---------------------------------------------------------------------------
__global__ __launch_bounds__(512, 2) void gemm_kscore_rot_kernel(
    const unsigned short* __restrict__ A, const unsigned short* __restrict__ W,
    const unsigned short* __restrict__ Cpad, const float* __restrict__ qkb,
    const float* __restrict__ kb, const float* __restrict__ qv,
    const float2* __restrict__ tab, float* __restrict__ sw_t,
    float* __restrict__ Z) {
  constexpr int K = 2048;
  constexpr int NT = K / 32;               // 64 K-tiles
  // buf i: A @ i*16384 (256x32 shorts), B @ i*16384+8192; C @ 49152 + i*512
  __shared__ unsigned short Ls[3 * 16384 + 3 * 512];

  const int tid = threadIdx.x;
  const int lane = tid & 63, wave = tid >> 6;
  const int wr = wave >> 2, wc = wave & 3;           // 2 x 4 waves
  const int l15 = lane & 15, lk = lane >> 4;

  // XCD swizzle (bijective, 256 wgs / 8 XCDs)
  const int orig = blockIdx.x;
  const int wgid = (orig & 7) * 32 + (orig >> 3);
  const int bm = wgid >> 2;                          // 0..63
  const int bn = wgid & 3;                           // 0..3
  const int b  = bm >> 3;

  // ---- staging sources (linear; no swizzle needed at BK=32) ---------------
  const unsigned short* Asrc = A + ((size_t)(bm * 256 + (tid >> 2))) * K + (tid & 3) * 8;
  const unsigned short* Bsrc = W + ((size_t)(bn * 256 + (tid >> 2))) * K + (tid & 3) * 8;
  const unsigned short* Csrc =
      Cpad + ((size_t)(b * 128 + bn * 4 + ((lane >> 2) & 3))) * K + (lane & 3) * 8;
  const int wave512 = wave * 512;
  unsigned short* Lc = Ls + 49152;

  // ---- accumulators -------------------------------------------------------
  f32x4 acc[8][4];
  f32x4 accc[8];
#pragma unroll
  for (int i = 0; i < 8; ++i) {
    accc[i] = (f32x4){0.f, 0.f, 0.f, 0.f};
#pragma unroll
    for (int j = 0; j < 4; ++j) acc[i][j] = (f32x4){0.f, 0.f, 0.f, 0.f};
  }

  // ---- LDS read bases (shorts), row stride 32 -----------------------------
  int rowA[8], rowB[4];
#pragma unroll
  for (int mi = 0; mi < 8; ++mi) rowA[mi] = (wr * 128 + mi * 16 + l15) * 32;
#pragma unroll
  for (int nj = 0; nj < 4; ++nj) rowB[nj] = (wc * 64 + nj * 16 + l15) * 32;
  const int rowC = l15 * 32;
  const int lko  = lk * 8;

#define STAGE(bufi, kb_) {                                                  \
    unsigned short* d_ = Ls + (bufi) * 16384 + wave512;                     \
    gld16(Asrc + (kb_),            d_);                                     \
    gld16(Asrc + 128 * K + (kb_),  d_ + 4096);                              \
    gld16(Bsrc + (kb_),            d_ + 8192);                              \
    gld16(Bsrc + 128 * K + (kb_),  d_ + 12288);                             \
    if (wave == 0) gld16(Csrc + (kb_), Lc + (bufi) * 512); }

  // ---- prologue: tiles 0 -> buf0, 1 -> buf1 -------------------------------
  STAGE(0, 0);
  STAGE(1, 32);
  if (wave == 0) { VM5(); } else { VM4(); }   // tile 0 landed; tile 1 in flight
  SBAR();

  // ---- main loop: 1 barrier per tile --------------------------------------
  int cur = 0, ib = 2;
  for (int t = 0; t < NT; ++t) {
    if (t + 2 < NT) STAGE(ib, (t + 2) * 32);   // dest freed by prev barrier
    const unsigned short* bufA = Ls + cur * 16384;
    const unsigned short* bufB = bufA + 8192;
    const unsigned short* bufC = Lc + cur * 512;
    bf16x8 af[8], bfr[4], cf;
#pragma unroll
    for (int mi = 0; mi < 8; ++mi)
      af[mi] = *(const bf16x8*)(bufA + rowA[mi] + lko);
#pragma unroll
    for (int nj = 0; nj < 4; ++nj)
      bfr[nj] = *(const bf16x8*)(bufB + rowB[nj] + lko);
    cf = *(const bf16x8*)(bufC + rowC + lko);
    __builtin_amdgcn_s_setprio(1);
#pragma unroll
    for (int mi = 0; mi < 8; ++mi) {
      accc[mi] = __builtin_amdgcn_mfma_f32_16x16x32_bf16(af[mi], cf,
                                                         accc[mi], 0, 0, 0);
#pragma unroll
      for (int nj = 0; nj < 4; ++nj)
        acc[mi][nj] = __builtin_amdgcn_mfma_f32_16x16x32_bf16(
            af[mi], bfr[nj], acc[mi][nj], 0, 0, 0);
    }
    __builtin_amdgcn_s_setprio(0);
    if (t == NT - 1) break;
    if (t + 2 < NT) {
      if (wave == 0) { VM5(); } else { VM4(); }  // tile t+1 landed; t+2 flies
    } else {
      VM0();                                     // drain for last tiles
    }
    SBAR();
    cur = (cur == 2) ? 0 : cur + 1;
    ib  = (ib == 2) ? 0 : ib + 1;
  }
#undef STAGE

  // ---- epilogue: rot score for head h = bn*4+wc, rows wr*128..+128 --------
  const int h  = bn * 4 + wc;
  const int rg = lk;                          // lane>>4
  const float* qb  = qv + ((size_t)b * 16 + h) * 128;
  const float* kbh = kb + h * 128;
  const float qkbv = qkb[b * 16 + h];
  float rowsum[8][4];
#pragma unroll
  for (int mi = 0; mi < 8; ++mi)
#pragma unroll
    for (int r = 0; r < 4; ++r) rowsum[mi][r] = 0.f;

  const int s0g = bm * 256 + wr * 128;        // global row base for this wave
  const float sgn = (l15 & 1) ? -1.f : 1.f;
#pragma unroll
  for (int nj = 0; nj < 4; ++nj) {
    const int c = nj * 16 + l15;
    const float qd   = qb[c];
    const float qps  = sgn * qb[c ^ 1];
    const float bias = kbh[c];
    const int i = c >> 1;
#pragma unroll
    for (int mi = 0; mi < 8; ++mi)
#pragma unroll
      for (int r = 0; r < 4; ++r) {
        const int t = s0g + mi * 16 + rg * 4 + r;
        const float2 sc = tab[(t & 2047) * 32 + i];
        rowsum[mi][r] += (acc[mi][nj][r] + bias) * (qd * sc.y + qps * sc.x);
      }
  }
#pragma unroll
  for (int mi = 0; mi < 8; ++mi)
#pragma unroll
    for (int r = 0; r < 4; ++r) {
      float v = rowsum[mi][r];
      v += __shfl_xor(v, 1);
      v += __shfl_xor(v, 2);
      v += __shfl_xor(v, 4);
      v += __shfl_xor(v, 8);
      rowsum[mi][r] = v;
    }
  // add plain score (col wc of accc, fetched from lane (lane&48)|wc) + bias.
  const int srcl = (lane & 48) | wc;
#pragma unroll
  for (int mi = 0; mi < 8; ++mi)
#pragma unroll
    for (int r = 0; r < 4; ++r)
      rowsum[mi][r] += __shfl(accc[mi][r], srcl) + qkbv;

  float zpart = 0.f;
  if (l15 == 0) {   // lanes 0,16,32,48 hold full sums for 32 rows each
#pragma unroll
    for (int mi = 0; mi < 8; ++mi)
#pragma unroll
      for (int r = 0; r < 4; ++r) {
        const int gr = s0g + mi * 16 + rg * 4 + r;     // global row 0..16383
        const float w = __expf(rowsum[mi][r] - 40.f);
        sw_t[(size_t)gr * 16 + h] = w;
        zpart += w;
      }
    zpart += __shfl_xor(zpart, 16);
    zpart += __shfl_xor(zpart, 32);
    if (lane == 0) atomicAdd(&Z[b * 16 + h], zpart);
  }
}

// ---------------------------------------------------------------------------
// 4. attn_wsum: part[tc][b][h][e] = sum_{t in chunk} w[b,t,h]*hs[b,t,e].
// ---------------------------------------------------------------------------
__global__ __launch_bounds__(256) void attn_wsum_kernel(
    const unsigned short* __restrict__ hs, const float* __restrict__ sw_t,
    float* __restrict__ part) {
  const int b = blockIdx.x, ech = blockIdx.y, tc = blockIdx.z;
  const int tid = threadIdx.x;
  const int e = ech * 512 + tid * 2;
  __shared__ float sw[128 * 16];
  {
    const float4* src = (const float4*)(sw_t + ((size_t)b * 2048 + tc * 128) * 16);
    float4* dst = (float4*)sw;
    dst[tid] = src[tid];
    dst[tid + 256] = src[tid + 256];
  }
  __syncthreads();
  float a0[16], a1[16];
#pragma unroll
  for (int h = 0; h < 16; ++h) { a0[h] = 0.f; a1[h] = 0.f; }
  const unsigned short* hp = hs + ((size_t)b * 2048 + tc * 128) * 2048 + e;
#pragma unroll 2
  for (int tt = 0; tt < 128; ++tt) {
    const unsigned hv = *(const unsigned*)(hp + (size_t)tt * 2048);
    const float h0 = __uint_as_float(hv << 16);
    const float h1 = __uint_as_float(hv & 0xffff0000u);
    const float4 w0 = *(const float4*)(sw + tt * 16 + 0);
    const float4 w1 = *(const float4*)(sw + tt * 16 + 4);
    const float4 w2 = *(const float4*)(sw + tt * 16 + 8);
    const float4 w3 = *(const float4*)(sw + tt * 16 + 12);
    const float wv[16] = {w0.x, w0.y, w0.z, w0.w, w1.x, w1.y, w1.z, w1.w,
                          w2.x, w2.y, w2.z, w2.w, w3.x, w3.y, w3.z, w3.w};
#pragma unroll
    for (int h = 0; h < 16; ++h) {
      a0[h] += wv[h] * h0;
      a1[h] += wv[h] * h1;
    }
  }
#pragma unroll
  for (int h = 0; h < 16; ++h) {
    float2 st = {a0[h], a1[h]};
    *(float2*)(part + (((size_t)tc * 8 + b) * 16 + h) * 2048 + e) = st;
  }
}

// ---------------------------------------------------------------------------
// 5. attn_comb: wsumN[bh][e] = (sum_tc part) / Z[bh].  128 blocks.
// ---------------------------------------------------------------------------
__global__ __launch_bounds__(256) void attn_comb_kernel(
    const float* __restrict__ part, const float* __restrict__ Z,
    float* __restrict__ wsumN) {
  const int bh = blockIdx.x, b = bh >> 4, h = bh & 15;
  const float zi = 1.f / Z[bh];
  for (int e = threadIdx.x; e < 2048; e += 256) {
    float s = 0.f;
#pragma unroll
    for (int tc = 0; tc < 16; ++tc)
      s += part[(((size_t)tc * 8 + b) * 16 + h) * 2048 + e];
    wsumN[(size_t)bh * 2048 + e] = s * zi;
  }
}

// ---------------------------------------------------------------------------
// 6. attn_vgemv: aout[bh][d] = v_w[h*128+d] . wsumN[bh] + v_b[h*128+d]
// ---------------------------------------------------------------------------
__global__ __launch_bounds__(256) void attn_vgemv_kernel(
    const float* __restrict__ vw, const float* __restrict__ vb,
    const float* __restrict__ wsumN, float* __restrict__ aout) {
  const int tid = threadIdx.x, lane = tid & 63, wave = tid >> 6;
  const int gw = blockIdx.x * 4 + wave;
  const int h = gw >> 7, d = gw & 127;
  const float* vr = vw + (size_t)gw * 2048;
  float p[8] = {0, 0, 0, 0, 0, 0, 0, 0};
#pragma unroll
  for (int it = 0; it < 8; ++it) {
    const int k = it * 256 + lane * 4;
    float4 wv = *(const float4*)(vr + k);
#pragma unroll
    for (int b = 0; b < 8; ++b) {
      float4 xv = *(const float4*)(wsumN + ((size_t)b * 16 + h) * 2048 + k);
      p[b] += wv.x * xv.x + wv.y * xv.y + wv.z * xv.z + wv.w * xv.w;
    }
  }
#pragma unroll
  for (int b = 0; b < 8; ++b)
    for (int m = 1; m < 64; m <<= 1) p[b] += __shfl_xor(p[b], m);
  if (lane == 0) {
    const float bb = vb[gw];
#pragma unroll
    for (int b = 0; b < 8; ++b)
      aout[((size_t)b * 16 + h) * 128 + d] = p[b] + bb;
  }
}

// ---------------------------------------------------------------------------
extern "C" void kernel_launch(void* const* d_in, const int* in_sizes, int n_in,
                              void* d_out, int out_size, void* d_ws, size_t ws_size,
                              hipStream_t stream) {
  (void)in_sizes; (void)n_in; (void)out_size; (void)ws_size;
  const float* hidden = (const float*)d_in[0];
  const int*   ids    = (const int*)d_in[1];
  const float* ln_w   = (const float*)d_in[2];
  const float* ln_b   = (const float*)d_in[3];
  const float* q_w    = (const float*)d_in[4];
  const float* q_b    = (const float*)d_in[5];
  const float* k_w    = (const float*)d_in[6];
  const float* k_b    = (const float*)d_in[7];
  const float* v_w    = (const float*)d_in[8];
  const float* v_b    = (const float*)d_in[9];
  const float* out_w  = (const float*)d_in[10];
  const float* out_b  = (const float*)d_in[11];
  float* out = (float*)d_out;

  char* ws = (char*)d_ws;
  unsigned short* hs  = (unsigned short*)ws; ws += (size_t)16384 * 2048 * 2;  // 64 MB
  unsigned short* Wk  = (unsigned short*)ws; ws += (size_t)1024 * 2048 * 2;   // 4 MB (rot)
  unsigned short* Cpad = (unsigned short*)ws; ws += (size_t)8 * 128 * 2048 * 2; // 4 MB
  float2* sctab = (float2*)ws; ws += (size_t)2048 * 32 * 8;                   // 512 KB
  float* qv     = (float*)ws; ws += (size_t)8 * 2048 * 4;
  float* hl     = (float*)ws; ws += (size_t)8 * 2048 * 4;
  float* aout   = (float*)ws; ws += (size_t)8 * 2048 * 4;
  float* sw_t   = (float*)ws; ws += (size_t)8 * 2048 * 16 * 4;                // 1 MB
  float* qkb    = (float*)ws; ws += 128 * 4;
  float* Zb     = (float*)ws; ws += 128 * 4;
  float* part   = (float*)ws; ws += (size_t)16 * 8 * 16 * 2048 * 4;           // 16 MB
  float* wsumN  = (float*)ws; ws += (size_t)128 * 2048 * 4;                   // 1 MB

  prep_kernel<<<18696, 256, 0, stream>>>(hidden, ids, ln_w, ln_b, k_w,
                                         hs, Wk, sctab, hl, Zb);
  gemv8_kernel<<<512, 256, 0, stream>>>(hl, q_w, q_b, qv);
  fold_c_kernel<<<256, 256, 0, stream>>>(qv, k_w, k_b, Cpad, qkb);
  gemm_kscore_rot_kernel<<<256, 512, 0, stream>>>(hs, Wk, Cpad, qkb, k_b, qv,
                                                  sctab, sw_t, Zb);
  attn_wsum_kernel<<<dim3(8, 4, 16), 256, 0, stream>>>(hs, sw_t, part);
  attn_comb_kernel<<<128, 256, 0, stream>>>(part, Zb, wsumN);
  attn_vgemv_kernel<<<512, 256, 0, stream>>>(v_w, v_b, wsumN, aout);
  gemv8_kernel<<<512, 256, 0, stream>>>(aout, out_w, out_b, out);
}

// Round 8
// 398.670 us; speedup vs baseline: 1.1902x; 1.0191x over previous
//
#include <hip/hip_runtime.h>
#include <hip/hip_bf16.h>
#include <cstdint>
#include <cstddef>

// ---------------------------------------------------------------------------
// NostARHeadAttention: LN -> {Q(last), K} proj -> RoPE(K) -> 1-query attn
// with V-elimination.
// R9: plain GEMM fused into rot GEMM as C-subtile. 401.2 us (part+comb wsum).
// R11: atomic wsum costs +20 vs part+comb. rot(BK=64, 2-barrier) = 90.6 us.
// R12: BK=32 triple-buffer 1-barrier: rot 96.3 us REGRESSED — "conflict-free
//      without swizzle" was WRONG (6.8M conflicts: all even-l15 lanes alias
//      one 4-bank group = 8-way). Other changes (wsum revert, fold_c split)
//      netted total 406.3.
// R13: 2-bit chunk XOR swizzle on the BK=32 layout: LDS[r][c'] holds global
//      chunk c'^((r>>1)&3) (pre-swizzled gld src, chunk=(tid&3)^((tid>>3)&3));
//      reads use chunk lk^((l15>>1)&3) (row term reduces to l15 for A/B/C).
//      Bank pattern becomes 2-way ({l15,l15+8}) = free. Data bit-identical.
// ---------------------------------------------------------------------------

using bf16x8 = __attribute__((ext_vector_type(8))) __bf16;
using f32x4  = __attribute__((ext_vector_type(4))) float;

__device__ __forceinline__ unsigned short f2bf(float f) {
  unsigned u = __float_as_uint(f);
  u += 0x7fffu + ((u >> 16) & 1u);   // RNE
  return (unsigned short)(u >> 16);
}

__device__ __forceinline__ void gld16(const void* g, void* l) {
  __builtin_amdgcn_global_load_lds((__attribute__((address_space(1))) void*)g,
                                   (__attribute__((address_space(3))) void*)l,
                                   16, 0, 0);
}

#define FENCE() asm volatile("" ::: "memory")
#define SBAR()  { FENCE(); __builtin_amdgcn_s_barrier(); FENCE(); }
#define VM5()   asm volatile("s_waitcnt vmcnt(5)" ::: "memory")
#define VM4()   asm volatile("s_waitcnt vmcnt(4)" ::: "memory")
#define VM0()   asm volatile("s_waitcnt vmcnt(0)" ::: "memory")

// ---------------------------------------------------------------------------
// 1. prep: fused ln (0..16383) + rot-only k_w f2bf (16384..18431) +
//    sctab (18432..18687) + ix+hlast+Z-zero (18688..18695).
// ---------------------------------------------------------------------------
__global__ __launch_bounds__(256) void prep_kernel(
    const float* __restrict__ hidden, const int* __restrict__ ids,
    const float* __restrict__ gw, const float* __restrict__ gb,
    const float* __restrict__ kw, unsigned short* __restrict__ hs,
    unsigned short* __restrict__ Wk, float2* __restrict__ tab,
    float* __restrict__ hl, float* __restrict__ Z) {
  const int blk = blockIdx.x, tid = threadIdx.x;
  const int wave = tid >> 6, lane = tid & 63;

  if (blk < 16384) {                       // ---- LayerNorm row -> bf16
    const size_t row = blk;
    const float* xr = hidden + row * 2048;
    float4 a = ((const float4*)xr)[tid];
    float4 b = ((const float4*)xr)[tid + 256];
    float s  = a.x + a.y + a.z + a.w + b.x + b.y + b.z + b.w;
    float ss = a.x*a.x + a.y*a.y + a.z*a.z + a.w*a.w +
               b.x*b.x + b.y*b.y + b.z*b.z + b.w*b.w;
    for (int m = 1; m < 64; m <<= 1) { s += __shfl_xor(s, m); ss += __shfl_xor(ss, m); }
    __shared__ float rs[4], rss[4];
    if (lane == 0) { rs[wave] = s; rss[wave] = ss; }
    __syncthreads();
    s  = rs[0] + rs[1] + rs[2] + rs[3];
    ss = rss[0] + rss[1] + rss[2] + rss[3];
    const float mu = s * (1.f / 2048.f);
    const float var = ss * (1.f / 2048.f) - mu * mu;
    const float r = rsqrtf(var + 1e-5f);
    const int i0 = tid * 4, i1 = 1024 + tid * 4;
    ushort4 p0 = {f2bf((a.x - mu) * r * gw[i0 + 0] + gb[i0 + 0]),
                  f2bf((a.y - mu) * r * gw[i0 + 1] + gb[i0 + 1]),
                  f2bf((a.z - mu) * r * gw[i0 + 2] + gb[i0 + 2]),
                  f2bf((a.w - mu) * r * gw[i0 + 3] + gb[i0 + 3])};
    ushort4 p1 = {f2bf((b.x - mu) * r * gw[i1 + 0] + gb[i1 + 0]),
                  f2bf((b.y - mu) * r * gw[i1 + 1] + gb[i1 + 1]),
                  f2bf((b.z - mu) * r * gw[i1 + 2] + gb[i1 + 2]),
                  f2bf((b.w - mu) * r * gw[i1 + 3] + gb[i1 + 3])};
    *(ushort4*)(hs + row * 2048 + i0) = p0;
    *(ushort4*)(hs + row * 2048 + i1) = p1;
  } else if (blk < 18432) {                // ---- rot cols of k_w -> bf16
    // Wk row r (0..1023) <- k_w row (r>>6)*128 + (r&63)  (head-major, 64/head)
    const size_t i4 = (size_t)(blk - 16384) * 256 + tid;   // 16B units
    const int r = (int)(i4 >> 9);
    const int col4 = (int)(i4 & 511);
    const size_t src4 = ((size_t)((r >> 6) * 128 + (r & 63))) * 512 + col4;
    float4 v = ((const float4*)kw)[src4];
    ushort4 o = {f2bf(v.x), f2bf(v.y), f2bf(v.z), f2bf(v.w)};
    ((ushort4*)Wk)[i4] = o;
  } else if (blk < 18688) {                // ---- sin/cos table (8 t / block)
    const int t = (blk - 18432) * 8 + (tid >> 5);
    const int i = tid & 31;
    const float inv = exp2f(-(float)i * (13.287712379549449f / 32.f));
    const float ang = (float)t * inv;
    tab[t * 32 + i] = make_float2(sinf(ang), cosf(ang));
  } else {                                 // ---- last-token index + LN + Z=0
    const int b = blk - 18688;
    if (tid < 16) Z[b * 16 + tid] = 0.f;
    int best = -1;
    for (int t = tid; t < 2048; t += 256)
      if (ids[b * 2048 + t] != 50257) best = (t > best) ? t : best;
    for (int m = 1; m < 64; m <<= 1) {
      int o = __shfl_xor(best, m);
      best = (o > best) ? o : best;
    }
    __shared__ int rb[4];
    if (lane == 0) rb[wave] = best;
    __syncthreads();
    int ix = rb[0];
    for (int w = 1; w < 4; ++w) ix = (rb[w] > ix) ? rb[w] : ix;
    ix = (ix < 0) ? 0 : ix;
    const float* xr = hidden + ((size_t)b * 2048 + ix) * 2048;
    float4 a = ((const float4*)xr)[tid];
    float4 c = ((const float4*)xr)[tid + 256];
    float s  = a.x + a.y + a.z + a.w + c.x + c.y + c.z + c.w;
    float ss = a.x*a.x + a.y*a.y + a.z*a.z + a.w*a.w +
               c.x*c.x + c.y*c.y + c.z*c.z + c.w*c.w;
    for (int m = 1; m < 64; m <<= 1) { s += __shfl_xor(s, m); ss += __shfl_xor(ss, m); }
    __shared__ float rs2[4], rss2[4];
    if (lane == 0) { rs2[wave] = s; rss2[wave] = ss; }
    __syncthreads();
    s  = rs2[0] + rs2[1] + rs2[2] + rs2[3];
    ss = rss2[0] + rss2[1] + rss2[2] + rss2[3];
    const float mu = s * (1.f / 2048.f);
    const float var = ss * (1.f / 2048.f) - mu * mu;
    const float r = rsqrtf(var + 1e-5f);
    const int i0 = tid * 4, i1 = 1024 + tid * 4;
    float* yo = hl + (size_t)b * 2048;
    yo[i0 + 0] = (a.x - mu) * r * gw[i0 + 0] + gb[i0 + 0];
    yo[i0 + 1] = (a.y - mu) * r * gw[i0 + 1] + gb[i0 + 1];
    yo[i0 + 2] = (a.z - mu) * r * gw[i0 + 2] + gb[i0 + 2];
    yo[i0 + 3] = (a.w - mu) * r * gw[i0 + 3] + gb[i0 + 3];
    yo[i1 + 0] = (c.x - mu) * r * gw[i1 + 0] + gb[i1 + 0];
    yo[i1 + 1] = (c.y - mu) * r * gw[i1 + 1] + gb[i1 + 1];
    yo[i1 + 2] = (c.z - mu) * r * gw[i1 + 2] + gb[i1 + 2];
    yo[i1 + 3] = (c.w - mu) * r * gw[i1 + 3] + gb[i1 + 3];
  }
}

// ---------------------------------------------------------------------------
// 2. GEMV: Y[8][2048] = X[8][2048] @ W^T + bias (fp32), 512 blocks.
// ---------------------------------------------------------------------------
__global__ __launch_bounds__(256) void gemv8_kernel(const float* __restrict__ X,
                                                    const float* __restrict__ W,
                                                    const float* __restrict__ bias,
                                                    float* __restrict__ Y) {
  const int tid = threadIdx.x, lane = tid & 63, wave = tid >> 6;
  const int e = blockIdx.x * 4 + wave;
  const float* wr = W + (size_t)e * 2048;
  float p[8] = {0, 0, 0, 0, 0, 0, 0, 0};
#pragma unroll
  for (int it = 0; it < 8; ++it) {
    const int k = it * 256 + lane * 4;
    float4 wv = *(const float4*)(wr + k);
#pragma unroll
    for (int b = 0; b < 8; ++b) {
      float4 xv = *(const float4*)(X + b * 2048 + k);
      p[b] += wv.x * xv.x + wv.y * xv.y + wv.z * xv.z + wv.w * xv.w;
    }
  }
#pragma unroll
  for (int b = 0; b < 8; ++b)
    for (int m = 1; m < 64; m <<= 1) p[b] += __shfl_xor(p[b], m);
  if (lane == 0) {
    const float bb = bias[e];
#pragma unroll
    for (int b = 0; b < 8; ++b) Y[(size_t)b * 2048 + e] = p[b] + bb;
  }
}

// ---------------------------------------------------------------------------
// 2b. fold_c: C[b,h,e] = sum_{c=64..127} q[b,h*128+c] * k_w[h*128+c, e]
//     -> Cpad rows 0..15 per b (bf16), plus qkb[b,h] = sum kb*q.
//     256 blocks: (bh, e-half); each thread 4 e over 64 c rows.
// ---------------------------------------------------------------------------
__global__ __launch_bounds__(256) void fold_c_kernel(
    const float* __restrict__ qv, const float* __restrict__ kw,
    const float* __restrict__ kb, unsigned short* __restrict__ Cpad,
    float* __restrict__ qkb) {
  const int blk = blockIdx.x, bh = blk >> 1, half = blk & 1;
  const int b = bh >> 4, h = bh & 15;
  const int tid = threadIdx.x;
  const float* qh = qv + ((size_t)b * 16 + h) * 128 + 64;
  const int e0 = half * 1024 + tid * 4;
  float acc[4] = {0, 0, 0, 0};
#pragma unroll 4
  for (int c = 0; c < 64; ++c) {
    const float qc = qh[c];
    const float4 v = *(const float4*)(kw + ((size_t)(h * 128 + 64 + c)) * 2048 + e0);
    acc[0] += qc * v.x; acc[1] += qc * v.y; acc[2] += qc * v.z; acc[3] += qc * v.w;
  }
  ushort4 o = {f2bf(acc[0]), f2bf(acc[1]), f2bf(acc[2]), f2bf(acc[3])};
  *(ushort4*)(Cpad + ((size_t)b * 128 + h) * 2048 + e0) = o;
  if (half == 0 && tid < 64) {
    float p = kb[h * 128 + 64 + tid] * qh[tid];
    for (int m = 1; m < 64; m <<= 1) p += __shfl_xor(p, m);
    if (tid == 0) qkb[bh] = p;
  }
}

// ---------------------------------------------------------------------------
// 3. gemm_kscore_rot: 256^2 tile, BK=32, 8 waves (2Mx4N), TRIPLE-buffered
//    LDS (99 KB), ONE barrier per tile; 2-bit chunk XOR swizzle:
//    LDS[r][c'] = global chunk c'^((r>>1)&3) via pre-swizzled gld source
//    (chunk=(tid&3)^((tid>>3)&3)); reads at chunk lk^((l15>>1)&3) -> 2-way
//    bank aliasing (free). Data delivered to MFMA bit-identical to R11/R12.
//    FUSED plain score C-subtile -> accc. Epilogue: rot dot w/ rotated q +
//    kb, + shfl'd plain col + qkb, exp(sc-40) -> sw_t, Z atomicAdd.
// ---------------------------------------------------------------------------
__global__ __launch_bounds__(512, 2) void gemm_kscore_rot_kernel(
    const unsigned short* __restrict__ A, const unsigned short* __restrict__ W,
    const unsigned short* __restrict__ Cpad, const float* __restrict__ qkb,
    const float* __restrict__ kb, const float* __restrict__ qv,
    const float2* __restrict__ tab, float* __restrict__ sw_t,
    float* __restrict__ Z) {
  constexpr int K = 2048;
  constexpr int NT = K / 32;               // 64 K-tiles
  // buf i: A @ i*16384 (256x32 shorts), B @ i*16384+8192; C @ 49152 + i*512
  __shared__ unsigned short Ls[3 * 16384 + 3 * 512];

  const int tid = threadIdx.x;
  const int lane = tid & 63, wave = tid >> 6;
  const int wr = wave >> 2, wc = wave & 3;           // 2 x 4 waves
  const int l15 = lane & 15, lk = lane >> 4;

  // XCD swizzle (bijective, 256 wgs / 8 XCDs)
  const int orig = blockIdx.x;
  const int wgid = (orig & 7) * 32 + (orig >> 3);
  const int bm = wgid >> 2;                          // 0..63
  const int bn = wgid & 3;                           // 0..3
  const int b  = bm >> 3;

  // ---- staging sources (pre-swizzled chunk: c = (tid&3) ^ ((tid>>3)&3)) ---
  const int schunk = (tid & 3) ^ ((tid >> 3) & 3);
  const unsigned short* Asrc = A + ((size_t)(bm * 256 + (tid >> 2))) * K + schunk * 8;
  const unsigned short* Bsrc = W + ((size_t)(bn * 256 + (tid >> 2))) * K + schunk * 8;
  const int cchunk = (lane & 3) ^ ((lane >> 3) & 3);
  const unsigned short* Csrc =
      Cpad + ((size_t)(b * 128 + bn * 4 + ((lane >> 2) & 3))) * K + cchunk * 8;
  const int wave512 = wave * 512;
  unsigned short* Lc = Ls + 49152;

  // ---- accumulators -------------------------------------------------------
  f32x4 acc[8][4];
  f32x4 accc[8];
#pragma unroll
  for (int i = 0; i < 8; ++i) {
    accc[i] = (f32x4){0.f, 0.f, 0.f, 0.f};
#pragma unroll
    for (int j = 0; j < 4; ++j) acc[i][j] = (f32x4){0.f, 0.f, 0.f, 0.f};
  }

  // ---- LDS read bases (shorts), row stride 32; swizzled chunk per lane ----
  int rowA[8], rowB[4];
#pragma unroll
  for (int mi = 0; mi < 8; ++mi) rowA[mi] = (wr * 128 + mi * 16 + l15) * 32;
#pragma unroll
  for (int nj = 0; nj < 4; ++nj) rowB[nj] = (wc * 64 + nj * 16 + l15) * 32;
  const int rowC = l15 * 32;
  const int lko  = (lk ^ ((l15 >> 1) & 3)) * 8;      // swizzled read chunk

#define STAGE(bufi, kb_) {                                                  \
    unsigned short* d_ = Ls + (bufi) * 16384 + wave512;                     \
    gld16(Asrc + (kb_),            d_);                                     \
    gld16(Asrc + 128 * K + (kb_),  d_ + 4096);                              \
    gld16(Bsrc + (kb_),            d_ + 8192);                              \
    gld16(Bsrc + 128 * K + (kb_),  d_ + 12288);                             \
    if (wave == 0) gld16(Csrc + (kb_), Lc + (bufi) * 512); }

  // ---- prologue: tiles 0 -> buf0, 1 -> buf1 -------------------------------
  STAGE(0, 0);
  STAGE(1, 32);
  if (wave == 0) { VM5(); } else { VM4(); }   // tile 0 landed; tile 1 in flight
  SBAR();

  // ---- main loop: 1 barrier per tile --------------------------------------
  int cur = 0, ib = 2;
  for (int t = 0; t < NT; ++t) {
    if (t + 2 < NT) STAGE(ib, (t + 2) * 32);   // dest freed by prev barrier
    const unsigned short* bufA = Ls + cur * 16384;
    const unsigned short* bufB = bufA + 8192;
    const unsigned short* bufC = Lc + cur * 512;
    bf16x8 af[8], bfr[4], cf;
#pragma unroll
    for (int mi = 0; mi < 8; ++mi)
      af[mi] = *(const bf16x8*)(bufA + rowA[mi] + lko);
#pragma unroll
    for (int nj = 0; nj < 4; ++nj)
      bfr[nj] = *(const bf16x8*)(bufB + rowB[nj] + lko);
    cf = *(const bf16x8*)(bufC + rowC + lko);
    __builtin_amdgcn_s_setprio(1);
#pragma unroll
    for (int mi = 0; mi < 8; ++mi) {
      accc[mi] = __builtin_amdgcn_mfma_f32_16x16x32_bf16(af[mi], cf,
                                                         accc[mi], 0, 0, 0);
#pragma unroll
      for (int nj = 0; nj < 4; ++nj)
        acc[mi][nj] = __builtin_amdgcn_mfma_f32_16x16x32_bf16(
            af[mi], bfr[nj], acc[mi][nj], 0, 0, 0);
    }
    __builtin_amdgcn_s_setprio(0);
    if (t == NT - 1) break;
    if (t + 2 < NT) {
      if (wave == 0) { VM5(); } else { VM4(); }  // tile t+1 landed; t+2 flies
    } else {
      VM0();                                     // drain for last tiles
    }
    SBAR();
    cur = (cur == 2) ? 0 : cur + 1;
    ib  = (ib == 2) ? 0 : ib + 1;
  }
#undef STAGE

  // ---- epilogue: rot score for head h = bn*4+wc, rows wr*128..+128 --------
  const int h  = bn * 4 + wc;
  const int rg = lk;                          // lane>>4
  const float* qb  = qv + ((size_t)b * 16 + h) * 128;
  const float* kbh = kb + h * 128;
  const float qkbv = qkb[b * 16 + h];
  float rowsum[8][4];
#pragma unroll
  for (int mi = 0; mi < 8; ++mi)
#pragma unroll
    for (int r = 0; r < 4; ++r) rowsum[mi][r] = 0.f;

  const int s0g = bm * 256 + wr * 128;        // global row base for this wave
  const float sgn = (l15 & 1) ? -1.f : 1.f;
#pragma unroll
  for (int nj = 0; nj < 4; ++nj) {
    const int c = nj * 16 + l15;
    const float qd   = qb[c];
    const float qps  = sgn * qb[c ^ 1];
    const float bias = kbh[c];
    const int i = c >> 1;
#pragma unroll
    for (int mi = 0; mi < 8; ++mi)
#pragma unroll
      for (int r = 0; r < 4; ++r) {
        const int t = s0g + mi * 16 + rg * 4 + r;
        const float2 sc = tab[(t & 2047) * 32 + i];
        rowsum[mi][r] += (acc[mi][nj][r] + bias) * (qd * sc.y + qps * sc.x);
      }
  }
#pragma unroll
  for (int mi = 0; mi < 8; ++mi)
#pragma unroll
    for (int r = 0; r < 4; ++r) {
      float v = rowsum[mi][r];
      v += __shfl_xor(v, 1);
      v += __shfl_xor(v, 2);
      v += __shfl_xor(v, 4);
      v += __shfl_xor(v, 8);
      rowsum[mi][r] = v;
    }
  // add plain score (col wc of accc, fetched from lane (lane&48)|wc) + bias.
  const int srcl = (lane & 48) | wc;
#pragma unroll
  for (int mi = 0; mi < 8; ++mi)
#pragma unroll
    for (int r = 0; r < 4; ++r)
      rowsum[mi][r] += __shfl(accc[mi][r], srcl) + qkbv;

  float zpart = 0.f;
  if (l15 == 0) {   // lanes 0,16,32,48 hold full sums for 32 rows each
#pragma unroll
    for (int mi = 0; mi < 8; ++mi)
#pragma unroll
      for (int r = 0; r < 4; ++r) {
        const int gr = s0g + mi * 16 + rg * 4 + r;     // global row 0..16383
        const float w = __expf(rowsum[mi][r] - 40.f);
        sw_t[(size_t)gr * 16 + h] = w;
        zpart += w;
      }
    zpart += __shfl_xor(zpart, 16);
    zpart += __shfl_xor(zpart, 32);
    if (lane == 0) atomicAdd(&Z[b * 16 + h], zpart);
  }
}

// ---------------------------------------------------------------------------
// 4. attn_wsum: part[tc][b][h][e] = sum_{t in chunk} w[b,t,h]*hs[b,t,e].
// ---------------------------------------------------------------------------
__global__ __launch_bounds__(256) void attn_wsum_kernel(
    const unsigned short* __restrict__ hs, const float* __restrict__ sw_t,
    float* __restrict__ part) {
  const int b = blockIdx.x, ech = blockIdx.y, tc = blockIdx.z;
  const int tid = threadIdx.x;
  const int e = ech * 512 + tid * 2;
  __shared__ float sw[128 * 16];
  {
    const float4* src = (const float4*)(sw_t + ((size_t)b * 2048 + tc * 128) * 16);
    float4* dst = (float4*)sw;
    dst[tid] = src[tid];
    dst[tid + 256] = src[tid + 256];
  }
  __syncthreads();
  float a0[16], a1[16];
#pragma unroll
  for (int h = 0; h < 16; ++h) { a0[h] = 0.f; a1[h] = 0.f; }
  const unsigned short* hp = hs + ((size_t)b * 2048 + tc * 128) * 2048 + e;
#pragma unroll 2
  for (int tt = 0; tt < 128; ++tt) {
    const unsigned hv = *(const unsigned*)(hp + (size_t)tt * 2048);
    const float h0 = __uint_as_float(hv << 16);
    const float h1 = __uint_as_float(hv & 0xffff0000u);
    const float4 w0 = *(const float4*)(sw + tt * 16 + 0);
    const float4 w1 = *(const float4*)(sw + tt * 16 + 4);
    const float4 w2 = *(const float4*)(sw + tt * 16 + 8);
    const float4 w3 = *(const float4*)(sw + tt * 16 + 12);
    const float wv[16] = {w0.x, w0.y, w0.z, w0.w, w1.x, w1.y, w1.z, w1.w,
                          w2.x, w2.y, w2.z, w2.w, w3.x, w3.y, w3.z, w3.w};
#pragma unroll
    for (int h = 0; h < 16; ++h) {
      a0[h] += wv[h] * h0;
      a1[h] += wv[h] * h1;
    }
  }
#pragma unroll
  for (int h = 0; h < 16; ++h) {
    float2 st = {a0[h], a1[h]};
    *(float2*)(part + (((size_t)tc * 8 + b) * 16 + h) * 2048 + e) = st;
  }
}

// ---------------------------------------------------------------------------
// 5. attn_comb: wsumN[bh][e] = (sum_tc part) / Z[bh].  128 blocks.
// ---------------------------------------------------------------------------
__global__ __launch_bounds__(256) void attn_comb_kernel(
    const float* __restrict__ part, const float* __restrict__ Z,
    float* __restrict__ wsumN) {
  const int bh = blockIdx.x, b = bh >> 4, h = bh & 15;
  const float zi = 1.f / Z[bh];
  for (int e = threadIdx.x; e < 2048; e += 256) {
    float s = 0.f;
#pragma unroll
    for (int tc = 0; tc < 16; ++tc)
      s += part[(((size_t)tc * 8 + b) * 16 + h) * 2048 + e];
    wsumN[(size_t)bh * 2048 + e] = s * zi;
  }
}

// ---------------------------------------------------------------------------
// 6. attn_vgemv: aout[bh][d] = v_w[h*128+d] . wsumN[bh] + v_b[h*128+d]
// ---------------------------------------------------------------------------
__global__ __launch_bounds__(256) void attn_vgemv_kernel(
    const float* __restrict__ vw, const float* __restrict__ vb,
    const float* __restrict__ wsumN, float* __restrict__ aout) {
  const int tid = threadIdx.x, lane = tid & 63, wave = tid >> 6;
  const int gw = blockIdx.x * 4 + wave;
  const int h = gw >> 7, d = gw & 127;
  const float* vr = vw + (size_t)gw * 2048;
  float p[8] = {0, 0, 0, 0, 0, 0, 0, 0};
#pragma unroll
  for (int it = 0; it < 8; ++it) {
    const int k = it * 256 + lane * 4;
    float4 wv = *(const float4*)(vr + k);
#pragma unroll
    for (int b = 0; b < 8; ++b) {
      float4 xv = *(const float4*)(wsumN + ((size_t)b * 16 + h) * 2048 + k);
      p[b] += wv.x * xv.x + wv.y * xv.y + wv.z * xv.z + wv.w * xv.w;
    }
  }
#pragma unroll
  for (int b = 0; b < 8; ++b)
    for (int m = 1; m < 64; m <<= 1) p[b] += __shfl_xor(p[b], m);
  if (lane == 0) {
    const float bb = vb[gw];
#pragma unroll
    for (int b = 0; b < 8; ++b)
      aout[((size_t)b * 16 + h) * 128 + d] = p[b] + bb;
  }
}

// ---------------------------------------------------------------------------
extern "C" void kernel_launch(void* const* d_in, const int* in_sizes, int n_in,
                              void* d_out, int out_size, void* d_ws, size_t ws_size,
                              hipStream_t stream) {
  (void)in_sizes; (void)n_in; (void)out_size; (void)ws_size;
  const float* hidden = (const float*)d_in[0];
  const int*   ids    = (const int*)d_in[1];
  const float* ln_w   = (const float*)d_in[2];
  const float* ln_b   = (const float*)d_in[3];
  const float* q_w    = (const float*)d_in[4];
  const float* q_b    = (const float*)d_in[5];
  const float* k_w    = (const float*)d_in[6];
  const float* k_b    = (const float*)d_in[7];
  const float* v_w    = (const float*)d_in[8];
  const float* v_b    = (const float*)d_in[9];
  const float* out_w  = (const float*)d_in[10];
  const float* out_b  = (const float*)d_in[11];
  float* out = (float*)d_out;

  char* ws = (char*)d_ws;
  unsigned short* hs  = (unsigned short*)ws; ws += (size_t)16384 * 2048 * 2;  // 64 MB
  unsigned short* Wk  = (unsigned short*)ws; ws += (size_t)1024 * 2048 * 2;   // 4 MB (rot)
  unsigned short* Cpad = (unsigned short*)ws; ws += (size_t)8 * 128 * 2048 * 2; // 4 MB
  float2* sctab = (float2*)ws; ws += (size_t)2048 * 32 * 8;                   // 512 KB
  float* qv     = (float*)ws; ws += (size_t)8 * 2048 * 4;
  float* hl     = (float*)ws; ws += (size_t)8 * 2048 * 4;
  float* aout   = (float*)ws; ws += (size_t)8 * 2048 * 4;
  float* sw_t   = (float*)ws; ws += (size_t)8 * 2048 * 16 * 4;                // 1 MB
  float* qkb    = (float*)ws; ws += 128 * 4;
  float* Zb     = (float*)ws; ws += 128 * 4;
  float* part   = (float*)ws; ws += (size_t)16 * 8 * 16 * 2048 * 4;           // 16 MB
  float* wsumN  = (float*)ws; ws += (size_t)128 * 2048 * 4;                   // 1 MB

  prep_kernel<<<18696, 256, 0, stream>>>(hidden, ids, ln_w, ln_b, k_w,
                                         hs, Wk, sctab, hl, Zb);
  gemv8_kernel<<<512, 256, 0, stream>>>(hl, q_w, q_b, qv);
  fold_c_kernel<<<256, 256, 0, stream>>>(qv, k_w, k_b, Cpad, qkb);
  gemm_kscore_rot_kernel<<<256, 512, 0, stream>>>(hs, Wk, Cpad, qkb, k_b, qv,
                                                  sctab, sw_t, Zb);
  attn_wsum_kernel<<<dim3(8, 4, 16), 256, 0, stream>>>(hs, sw_t, part);
  attn_comb_kernel<<<128, 256, 0, stream>>>(part, Zb, wsumN);
  attn_vgemv_kernel<<<512, 256, 0, stream>>>(v_w, v_b, wsumN, aout);
  gemv8_kernel<<<512, 256, 0, stream>>>(aout, out_w, out_b, out);
}